// Round 1
// baseline (1933.711 us; speedup 1.0000x reference)
//
#include <hip/hip_runtime.h>
#include <math.h>

#define NSRC 10000
#define NEDGE 320000
#define EDIM 236
#define TOPN 6

// ---------------------------------------------------------------- top-k utils
struct KV { float v; int i; };

__device__ __forceinline__ bool kv_better(const KV a, const KV b) {
  return (a.v > b.v) || (a.v == b.v && a.i < b.i);
}

// merge sorted o into sorted d (both length TOPN, descending by kv_better)
__device__ __forceinline__ void kv_merge(KV d[TOPN], const KV o[TOPN]) {
  KV r[TOPN];
  int ia = 0, ib = 0;
#pragma unroll
  for (int q = 0; q < TOPN; ++q) {
    bool takeA;
    if (ia >= TOPN) takeA = false;
    else if (ib >= TOPN) takeA = true;
    else takeA = kv_better(d[ia], o[ib]);
    r[q] = takeA ? d[ia] : o[ib];
    if (takeA) ia++; else ib++;
  }
#pragma unroll
  for (int q = 0; q < TOPN; ++q) d[q] = r[q];
}

// ---------------------------------------------------------------- small utils
__global__ void k_zero(float* __restrict__ p, int n) {
  int i = blockIdx.x * 256 + threadIdx.x;
  if (i < n) p[i] = 0.f;
}

__global__ void k_sentinel(float* __restrict__ out) {
  if (threadIdx.x == 0) out[0] = 1.0e9f;
}

// ---------------------------------------------------------------- weight prep
// W1cat[m][i*128+j] = conv_W1[i][m][j]   (shape [128][384])
__global__ void k_prep_w1cat(const float* __restrict__ cw1, float* __restrict__ w1cat) {
  int gid = blockIdx.x * 256 + threadIdx.x;
  if (gid >= 3 * 128 * 128) return;
  int i = gid >> 14;
  int m = (gid >> 7) & 127;
  int j = gid & 127;
  w1cat[m * 384 + i * 128 + j] = cw1[gid];
}

// WeW1cat[k][i*128+j] = sum_m We_i[k][m] * W1_i[m][j]   (shape [236][384])
__global__ void k_prep_wew1(const float* __restrict__ cew, const float* __restrict__ cw1,
                            float* __restrict__ wew1cat) {
  int b = blockIdx.x;            // 0..707 = i*236+k
  int i = b / EDIM;
  int k = b - i * EDIM;
  int j = threadIdx.x;           // 0..127
  const float* we = cew + ((size_t)i * EDIM + k) * 128;
  const float* w1 = cw1 + (size_t)i * 16384;
  float acc = 0.f;
  for (int m = 0; m < 128; ++m) acc = fmaf(we[m], w1[m * 128 + j], acc);
  wew1cat[k * 384 + i * 128 + j] = acc;
}

// bprime[i*128+j] = sum_m be_i[m] * W1_i[m][j]
__global__ void k_prep_bprime(const float* __restrict__ ceb, const float* __restrict__ cw1,
                              float* __restrict__ bprime) {
  int i = blockIdx.x;            // 0..2
  int j = threadIdx.x;           // 0..127
  const float* be = ceb + i * 128;
  const float* w1 = cw1 + (size_t)i * 16384;
  float acc = 0.f;
  for (int m = 0; m < 128; ++m) acc = fmaf(be[m], w1[m * 128 + j], acc);
  bprime[i * 128 + j] = acc;
}

// M1[(i*128+r)][j] = sum_c W2_i[r][c] * lin1_W[(i*128+c)][j]   (shape [384][128])
__global__ void k_prep_m1(const float* __restrict__ cw2, const float* __restrict__ l1w,
                          float* __restrict__ m1) {
  int b = blockIdx.x;            // 0..383 = i*128+r
  int i = b >> 7;
  int r = b & 127;
  int j = threadIdx.x;           // 0..127
  const float* w2 = cw2 + (size_t)i * 16384 + r * 128;
  float acc = 0.f;
  for (int c = 0; c < 128; ++c) acc = fmaf(w2[c], l1w[((size_t)i * 128 + c) * 128 + j], acc);
  m1[b * 128 + j] = acc;
}

// ---------------------------------------------------------------- segment sum
// agg[src[e]][:] += relu(path_feats[e][:])   via fp32 atomics (skip zeros)
__global__ __launch_bounds__(256) void k_segsum(const float* __restrict__ pf,
                                                const int* __restrict__ src,
                                                float* __restrict__ agg) {
  int gid = blockIdx.x * 256 + threadIdx.x;   // exact grid: NEDGE*59
  int e = gid / 59;
  int r = gid - e * 59;
  const float4 v = *(const float4*)(pf + (size_t)e * EDIM + r * 4);
  float* dst = agg + (size_t)src[e] * EDIM + r * 4;
  if (v.x > 0.f) atomicAdd(dst + 0, v.x);
  if (v.y > 0.f) atomicAdd(dst + 1, v.y);
  if (v.z > 0.f) atomicAdd(dst + 2, v.z);
  if (v.w > 0.f) atomicAdd(dst + 3, v.w);
}

// ---------------------------------------------------------------- fp32 GEMM
// C[M,N] = f(A'[M,K] @ B[K,N]); BM=BN=128, BK=8, 256 threads, 8x8 per thread.
// ATR: 0=none, 1=BN+relu on A-load (z = relu(g*(a-mean)*rstd + b))
// EPI: 0=store; 1=C=Cin+acc+bias, column stats; 2=relu(acc+bias);
//      3=acc+bias(+bias2); 4=acc+gatherTab[srcids[m]][:], column stats
template <int ATR, int EPI>
__global__ __launch_bounds__(256)
void gemm_k(const float* __restrict__ A, const float* __restrict__ B,
            float* __restrict__ C, int M, int K, int N,
            const float* __restrict__ bn_g, const float* __restrict__ bn_b,
            const float* __restrict__ bn_mean, const float* __restrict__ bn_rstd,
            const float* __restrict__ bias, const float* __restrict__ bias2,
            const float* __restrict__ Cin,
            const int* __restrict__ srcids, const float* __restrict__ gatherTab,
            float* __restrict__ colsum, float* __restrict__ colsumsq) {
  __shared__ float As[8][128];   // [k][m]
  __shared__ float Bs[8][128];   // [k][n]
  __shared__ float red[16][128];
  constexpr bool STATS = (EPI == 1 || EPI == 4);

  const int tid = threadIdx.x;
  const int tx = tid & 15;       // col group (8 cols)
  const int ty = tid >> 4;       // row group (8 rows)
  const int bm = blockIdx.x * 128;
  const int bn = blockIdx.y * 128;

  float acc[8][8];
#pragma unroll
  for (int i = 0; i < 8; ++i)
#pragma unroll
    for (int j = 0; j < 8; ++j) acc[i][j] = 0.f;

  for (int k0 = 0; k0 < K; k0 += 8) {
    // stage A tile (transposed into [k][m])
    {
      int r = tid >> 1;
      int cq = (tid & 1) << 2;
      float4 v = make_float4(0.f, 0.f, 0.f, 0.f);
      int row = bm + r;
      if (row < M) {
        const float* ap = A + (size_t)row * K + k0 + cq;
        if (k0 + cq + 4 <= K) {
          v = *(const float4*)ap;
        } else {
          float tmp[4] = {0.f, 0.f, 0.f, 0.f};
          for (int q = 0; q < 4; ++q)
            if (k0 + cq + q < K) tmp[q] = ap[q];
          v = make_float4(tmp[0], tmp[1], tmp[2], tmp[3]);
        }
      }
      if constexpr (ATR == 1) {
        float vv[4] = {v.x, v.y, v.z, v.w};
#pragma unroll
        for (int q = 0; q < 4; ++q) {
          int k = k0 + cq + q;
          if (k < K) {
            vv[q] = fmaxf(fmaf(bn_g[k], (vv[q] - bn_mean[k]) * bn_rstd[k], bn_b[k]), 0.f);
          } else {
            vv[q] = 0.f;
          }
        }
        v = make_float4(vv[0], vv[1], vv[2], vv[3]);
      }
      As[cq + 0][r] = v.x;
      As[cq + 1][r] = v.y;
      As[cq + 2][r] = v.z;
      As[cq + 3][r] = v.w;
    }
    // stage B tile
    {
      int r = tid >> 5;
      int c = (tid & 31) << 2;
      float4 v = make_float4(0.f, 0.f, 0.f, 0.f);
      int kk = k0 + r;
      if (kk < K) v = *(const float4*)(B + (size_t)kk * N + bn + c);
      *(float4*)&Bs[r][c] = v;
    }
    __syncthreads();
#pragma unroll
    for (int kk = 0; kk < 8; ++kk) {
      const float4 a0 = *(const float4*)&As[kk][ty * 8];
      const float4 a1 = *(const float4*)&As[kk][ty * 8 + 4];
      const float4 b0 = *(const float4*)&Bs[kk][tx * 8];
      const float4 b1 = *(const float4*)&Bs[kk][tx * 8 + 4];
      const float av[8] = {a0.x, a0.y, a0.z, a0.w, a1.x, a1.y, a1.z, a1.w};
      const float bv[8] = {b0.x, b0.y, b0.z, b0.w, b1.x, b1.y, b1.z, b1.w};
#pragma unroll
      for (int i = 0; i < 8; ++i)
#pragma unroll
        for (int j = 0; j < 8; ++j) acc[i][j] = fmaf(av[i], bv[j], acc[i][j]);
    }
    __syncthreads();
  }

  // epilogue
  const int nb = bn + tx * 8;
  float colS[8], colQ[8];
  if constexpr (STATS) {
#pragma unroll
    for (int j = 0; j < 8; ++j) { colS[j] = 0.f; colQ[j] = 0.f; }
  }
#pragma unroll
  for (int i = 0; i < 8; ++i) {
    int m = bm + ty * 8 + i;
    if (m < M) {
      float outv[8];
#pragma unroll
      for (int j = 0; j < 8; ++j) outv[j] = acc[i][j];
      if constexpr (EPI == 1) {
        const float* crow = Cin + (size_t)m * N + nb;
#pragma unroll
        for (int j = 0; j < 8; ++j) outv[j] += crow[j] + bias[nb + j];
      } else if constexpr (EPI == 2) {
#pragma unroll
        for (int j = 0; j < 8; ++j) outv[j] = fmaxf(outv[j] + bias[nb + j], 0.f);
      } else if constexpr (EPI == 3) {
#pragma unroll
        for (int j = 0; j < 8; ++j) {
          float bb = bias[nb + j];
          if (bias2) bb += bias2[nb + j];
          outv[j] += bb;
        }
      } else if constexpr (EPI == 4) {
        int s = srcids[m];
        const float* g = gatherTab + (size_t)s * N + nb;
#pragma unroll
        for (int j = 0; j < 8; ++j) outv[j] += g[j];
      }
      float* crow = C + (size_t)m * N + nb;
      *(float4*)crow = make_float4(outv[0], outv[1], outv[2], outv[3]);
      *(float4*)(crow + 4) = make_float4(outv[4], outv[5], outv[6], outv[7]);
      if constexpr (STATS) {
#pragma unroll
        for (int j = 0; j < 8; ++j) { colS[j] += outv[j]; colQ[j] += outv[j] * outv[j]; }
      }
    }
  }
  if constexpr (STATS) {
    *(float4*)&red[ty][tx * 8] = make_float4(colS[0], colS[1], colS[2], colS[3]);
    *(float4*)&red[ty][tx * 8 + 4] = make_float4(colS[4], colS[5], colS[6], colS[7]);
    __syncthreads();
    if (tid < 128) {
      float s = 0.f;
#pragma unroll
      for (int t = 0; t < 16; ++t) s += red[t][tid];
      atomicAdd(colsum + bn + tid, s);
    }
    __syncthreads();
    *(float4*)&red[ty][tx * 8] = make_float4(colQ[0], colQ[1], colQ[2], colQ[3]);
    *(float4*)&red[ty][tx * 8 + 4] = make_float4(colQ[4], colQ[5], colQ[6], colQ[7]);
    __syncthreads();
    if (tid < 128) {
      float s = 0.f;
#pragma unroll
      for (int t = 0; t < 16; ++t) s += red[t][tid];
      atomicAdd(colsumsq + bn + tid, s);
    }
  }
}

// ---------------------------------------------------------------- stat finalize
__global__ void k_finT(float* __restrict__ st) {
  int j = threadIdx.x;  // 384
  float mean = st[j] * (1.0f / NSRC);
  float var = st[384 + j] * (1.0f / NSRC) - mean * mean;
  st[768 + j] = mean;
  st[1152 + j] = rsqrtf(var + 1e-5f);
}

__global__ void k_finP(float* __restrict__ st, const float* __restrict__ g,
                       const float* __restrict__ b) {
  int j = threadIdx.x;  // 128
  float mean = st[j] * (1.0f / NEDGE);
  float var = st[128 + j] * (1.0f / NEDGE) - mean * mean;
  float rstd = rsqrtf(var + 1e-5f);
  float a = g[j] * rstd;
  st[256 + j] = a;              // scale
  st[384 + j] = b[j] - a * mean; // shift
}

// ---------------------------------------------------------------- scoring
// scores[e] = sum_j relu(a[j]*hpath[e][j] + c[j]) * w[j]; 16 lanes per row
__global__ __launch_bounds__(256) void k_score(const float* __restrict__ hpath,
                                               const float* __restrict__ aP,
                                               const float* __restrict__ cP,
                                               const float* __restrict__ w,
                                               float* __restrict__ scores) {
  const int row = blockIdx.x * 16 + (threadIdx.x >> 4);
  const int cg = threadIdx.x & 15;
  const float* hp = hpath + (size_t)row * 128 + cg * 8;
  const float4 x0 = *(const float4*)hp;
  const float4 x1 = *(const float4*)(hp + 4);
  const float xs[8] = {x0.x, x0.y, x0.z, x0.w, x1.x, x1.y, x1.z, x1.w};
  float part = 0.f;
#pragma unroll
  for (int q = 0; q < 8; ++q) {
    int j = cg * 8 + q;
    part += fmaxf(fmaf(aP[j], xs[q], cP[j]), 0.f) * w[j];
  }
#pragma unroll
  for (int o = 8; o >= 1; o >>= 1) part += __shfl_xor(part, o, 16);
  if (cg == 0) scores[row] = part;
}

// ---------------------------------------------------------------- top-k
__global__ __launch_bounds__(256) void k_top1(const float* __restrict__ scores,
                                              KV* __restrict__ cand) {
  KV t[TOPN];
#pragma unroll
  for (int q = 0; q < TOPN; ++q) { t[q].v = -INFINITY; t[q].i = 2147483647; }
  for (int e = blockIdx.x * 256 + threadIdx.x; e < NEDGE; e += 256 * 256) {
    float v = scores[e];
    if (v > t[TOPN - 1].v) {      // strict: equal keeps earlier (smaller) index
      t[TOPN - 1].v = v;
      t[TOPN - 1].i = e;
#pragma unroll
      for (int q = TOPN - 1; q > 0; --q) {
        if (t[q].v > t[q - 1].v) { KV tmp = t[q - 1]; t[q - 1] = t[q]; t[q] = tmp; }
      }
    }
  }
  __shared__ KV sh[128][TOPN];
  int tid = threadIdx.x;
  for (int s = 128; s >= 1; s >>= 1) {
    if (tid >= s && tid < 2 * s) {
#pragma unroll
      for (int q = 0; q < TOPN; ++q) sh[tid - s][q] = t[q];
    }
    __syncthreads();
    if (tid < s) kv_merge(t, sh[tid]);
    __syncthreads();
  }
  if (tid == 0) {
#pragma unroll
    for (int q = 0; q < TOPN; ++q) cand[blockIdx.x * TOPN + q] = t[q];
  }
}

__global__ __launch_bounds__(256) void k_top2(const KV* __restrict__ cand,
                                              float* __restrict__ outTail) {
  int tid = threadIdx.x;
  KV t[TOPN];
#pragma unroll
  for (int q = 0; q < TOPN; ++q) t[q] = cand[tid * TOPN + q];
  __shared__ KV sh[128][TOPN];
  for (int s = 128; s >= 1; s >>= 1) {
    if (tid >= s && tid < 2 * s) {
#pragma unroll
      for (int q = 0; q < TOPN; ++q) sh[tid - s][q] = t[q];
    }
    __syncthreads();
    if (tid < s) kv_merge(t, sh[tid]);
    __syncthreads();
  }
  if (tid == 0) {
#pragma unroll
    for (int q = 0; q < TOPN; ++q) {
      outTail[q] = t[q].v;
      outTail[TOPN + q] = (float)t[q].i;   // harness reads flat fp32
    }
  }
}

// ---------------------------------------------------------------- launch
extern "C" void kernel_launch(void* const* d_in, const int* in_sizes, int n_in,
                              void* d_out, int out_size, void* d_ws, size_t ws_size,
                              hipStream_t stream) {
  const float* paths_srcs = (const float*)d_in[0];
  const float* path_feats = (const float*)d_in[1];
  const int* src_ids = (const int*)d_in[2];
  const float* cew = (const float*)d_in[3];
  const float* ceb = (const float*)d_in[4];
  const float* cw1 = (const float*)d_in[5];
  const float* bng = (const float*)d_in[6];
  const float* bnbt = (const float*)d_in[7];
  const float* cw2 = (const float*)d_in[8];
  const float* l1w = (const float*)d_in[9];
  const float* l1b = (const float*)d_in[10];
  const float* l2w = (const float*)d_in[11];
  const float* l2b = (const float*)d_in[12];
  const float* psw = (const float*)d_in[13];
  const float* psb = (const float*)d_in[14];
  const float* ptw = (const float*)d_in[15];
  const float* ptb = (const float*)d_in[16];
  const float* pbg = (const float*)d_in[17];
  const float* pbb = (const float*)d_in[18];
  const float* scw = (const float*)d_in[19];
  float* out = (float*)d_out;
  float* ws = (float*)d_ws;

  // workspace layout (floats)
  float* w1cat = ws;                        // 49152
  float* wew1cat = w1cat + 49152;           // 90624
  float* bprime = wew1cat + 90624;          // 512
  float* m1 = bprime + 512;                 // 49152
  float* statsT = m1 + 49152;               // 1536: sum|sumsq|mean|rstd
  float* statsP = statsT + 1536;            // 512:  sum|sumsq|a|c
  float* agg = statsP + 512;                // 2360000
  float* T = agg + 2360000;                 // 3840000
  float* H1 = T + 3840000;                  // 1280000
  float* pre_src = H1 + 1280000;            // 1280000
  float* scores = pre_src + 1280000;        // 320000
  KV* cand = (KV*)(scores + 320000);        // 1536 KV = 3072 floats
  float* hpath = scores + 320000 + 3072;    // 40960000
  const size_t needed = (size_t)(49152 + 90624 + 512 + 49152 + 1536 + 512 + 2360000 +
                                 3840000 + 1280000 + 1280000 + 320000 + 3072 +
                                 40960000) * 4;
  if (ws_size < needed) {
    k_sentinel<<<1, 64, 0, stream>>>(out);  // distinguishable failure: out[0]=1e9
    return;
  }

  const float* np = nullptr;

  // weight prep
  k_prep_w1cat<<<192, 256, 0, stream>>>(cw1, w1cat);
  k_prep_wew1<<<708, 128, 0, stream>>>(cew, cw1, wew1cat);
  k_prep_bprime<<<3, 128, 0, stream>>>(ceb, cw1, bprime);
  k_prep_m1<<<384, 128, 0, stream>>>(cw2, l1w, m1);

  // zero accumulators (ws is poisoned 0xAA before every call)
  k_zero<<<(2360000 + 255) / 256, 256, 0, stream>>>(agg, 2360000);
  k_zero<<<8, 256, 0, stream>>>(statsT, 2048);  // statsT(1536)+statsP(512) contiguous

  // segment sum of relu(path_feats)
  k_segsum<<<NEDGE * 59 / 256, 256, 0, stream>>>(path_feats, src_ids, agg);

  // T = paths_srcs @ W1cat                       [10000,384]
  gemm_k<0, 0><<<dim3(79, 3), 256, 0, stream>>>(paths_srcs, w1cat, T, NSRC, 128, 384,
                                                np, np, np, np, np, np, np, nullptr, np,
                                                nullptr, nullptr);
  // T += agg @ WeW1cat + bprime, column stats
  gemm_k<0, 1><<<dim3(79, 3), 256, 0, stream>>>(agg, wew1cat, T, NSRC, EDIM, 384,
                                                np, np, np, np, bprime, np, T, nullptr,
                                                np, statsT, statsT + 384);
  k_finT<<<1, 384, 0, stream>>>(statsT);
  // H1 = relu(relu(BN(T)) @ M1 + lin1_b)         [10000,128]
  gemm_k<1, 2><<<dim3(79, 1), 256, 0, stream>>>(T, m1, H1, NSRC, 384, 128,
                                                bng, bnbt, statsT + 768, statsT + 1152,
                                                l1b, np, np, nullptr, np, nullptr, nullptr);
  // node_emb = H1 @ lin2_W + lin2_b  -> d_out
  gemm_k<0, 3><<<dim3(79, 1), 256, 0, stream>>>(H1, l2w, out, NSRC, 128, 128,
                                                np, np, np, np, l2b, np, np, nullptr, np,
                                                nullptr, nullptr);
  // pre_src = node_emb @ pe_src_W + (pe_src_b + pe_tgt_b)
  gemm_k<0, 3><<<dim3(79, 1), 256, 0, stream>>>(out, psw, pre_src, NSRC, 128, 128,
                                                np, np, np, np, psb, ptb, np, nullptr, np,
                                                nullptr, nullptr);
  // hpath = path_feats @ pe_tgt_W + pre_src[src_ids], column stats  [320000,128]
  gemm_k<0, 4><<<dim3(2500, 1), 256, 0, stream>>>(path_feats, ptw, hpath, NEDGE, EDIM, 128,
                                                  np, np, np, np, np, np, np, src_ids,
                                                  pre_src, statsP, statsP + 128);
  k_finP<<<1, 128, 0, stream>>>(statsP, pbg, pbb);
  // scores + top-6
  k_score<<<NEDGE / 16, 256, 0, stream>>>(hpath, statsP + 256, statsP + 384, scw, scores);
  k_top1<<<256, 256, 0, stream>>>(scores, cand);
  k_top2<<<1, 256, 0, stream>>>(cand, out + (size_t)NSRC * 128);
}

// Round 2
// 1158.756 us; speedup vs baseline: 1.6688x; 1.6688x over previous
//
#include <hip/hip_runtime.h>
#include <math.h>

#define NSRC 10000
#define NEDGE 320000
#define EDIM 236
#define TOPN 6

// ---------------------------------------------------------------- top-k utils
struct KV { float v; int i; };

__device__ __forceinline__ bool kv_better(const KV a, const KV b) {
  return (a.v > b.v) || (a.v == b.v && a.i < b.i);
}

// merge sorted o into sorted d (both length TOPN, descending by kv_better)
__device__ __forceinline__ void kv_merge(KV d[TOPN], const KV o[TOPN]) {
  KV r[TOPN];
  int ia = 0, ib = 0;
#pragma unroll
  for (int q = 0; q < TOPN; ++q) {
    bool takeA;
    if (ia >= TOPN) takeA = false;
    else if (ib >= TOPN) takeA = true;
    else takeA = kv_better(d[ia], o[ib]);
    r[q] = takeA ? d[ia] : o[ib];
    if (takeA) ia++; else ib++;
  }
#pragma unroll
  for (int q = 0; q < TOPN; ++q) d[q] = r[q];
}

// ---------------------------------------------------------------- small utils
__global__ void k_zero(float* __restrict__ p, int n) {
  int i = blockIdx.x * 256 + threadIdx.x;
  if (i < n) p[i] = 0.f;
}

__global__ void k_sentinel(float* __restrict__ out) {
  if (threadIdx.x == 0) out[0] = 1.0e9f;
}

// ---------------------------------------------------------------- weight prep
// W1cat[m][i*128+j] = conv_W1[i][m][j]   (shape [128][384])
__global__ void k_prep_w1cat(const float* __restrict__ cw1, float* __restrict__ w1cat) {
  int gid = blockIdx.x * 256 + threadIdx.x;
  if (gid >= 3 * 128 * 128) return;
  int i = gid >> 14;
  int m = (gid >> 7) & 127;
  int j = gid & 127;
  w1cat[m * 384 + i * 128 + j] = cw1[gid];
}

// WeW1cat[k][i*128+j] = sum_m We_i[k][m] * W1_i[m][j]   (shape [236][384])
__global__ void k_prep_wew1(const float* __restrict__ cew, const float* __restrict__ cw1,
                            float* __restrict__ wew1cat) {
  int b = blockIdx.x;            // 0..707 = i*236+k
  int i = b / EDIM;
  int k = b - i * EDIM;
  int j = threadIdx.x;           // 0..127
  const float* we = cew + ((size_t)i * EDIM + k) * 128;
  const float* w1 = cw1 + (size_t)i * 16384;
  float acc = 0.f;
  for (int m = 0; m < 128; ++m) acc = fmaf(we[m], w1[m * 128 + j], acc);
  wew1cat[k * 384 + i * 128 + j] = acc;
}

// bprime[i*128+j] = sum_m be_i[m] * W1_i[m][j]
__global__ void k_prep_bprime(const float* __restrict__ ceb, const float* __restrict__ cw1,
                              float* __restrict__ bprime) {
  int i = blockIdx.x;            // 0..2
  int j = threadIdx.x;           // 0..127
  const float* be = ceb + i * 128;
  const float* w1 = cw1 + (size_t)i * 16384;
  float acc = 0.f;
  for (int m = 0; m < 128; ++m) acc = fmaf(be[m], w1[m * 128 + j], acc);
  bprime[i * 128 + j] = acc;
}

// M1[(i*128+r)][j] = sum_c W2_i[r][c] * lin1_W[(i*128+c)][j]   (shape [384][128])
__global__ void k_prep_m1(const float* __restrict__ cw2, const float* __restrict__ l1w,
                          float* __restrict__ m1) {
  int b = blockIdx.x;            // 0..383 = i*128+r
  int i = b >> 7;
  int r = b & 127;
  int j = threadIdx.x;           // 0..127
  const float* w2 = cw2 + (size_t)i * 16384 + r * 128;
  float acc = 0.f;
  for (int c = 0; c < 128; ++c) acc = fmaf(w2[c], l1w[((size_t)i * 128 + c) * 128 + j], acc);
  m1[b * 128 + j] = acc;
}

// ---------------------------------------------------------------- CSR build
// histogram of src ids (320K atomics over 10K ints -- cheap)
__global__ __launch_bounds__(256) void k_hist(const int* __restrict__ src,
                                              int* __restrict__ counts) {
  int e = blockIdx.x * 256 + threadIdx.x;
  if (e < NEDGE) atomicAdd(&counts[src[e]], 1);
}

// single-block exclusive prefix sum over 10000 counts -> offsets + cursors
__global__ __launch_bounds__(256) void k_scan(const int* __restrict__ counts,
                                              int* __restrict__ offsets,
                                              int* __restrict__ cursor) {
  __shared__ int part[256];
  const int t = threadIdx.x;
  const int base = t * 40;               // 256*40 = 10240 >= 10000
  int s = 0;
  for (int k = 0; k < 40; ++k) {
    int i = base + k;
    if (i < NSRC) s += counts[i];
  }
  part[t] = s;
  __syncthreads();
  // Hillis-Steele inclusive scan
  for (int off = 1; off < 256; off <<= 1) {
    int v = (t >= off) ? part[t - off] : 0;
    __syncthreads();
    part[t] += v;
    __syncthreads();
  }
  int run = (t == 0) ? 0 : part[t - 1];  // exclusive
  for (int k = 0; k < 40; ++k) {
    int i = base + k;
    if (i < NSRC) {
      offsets[i] = run;
      cursor[i] = run;
      run += counts[i];
    }
  }
  if (t == 255) offsets[NSRC] = run;     // == NEDGE
}

// scatter edge ids into CSR order
__global__ __launch_bounds__(256) void k_scatter(const int* __restrict__ src,
                                                 int* __restrict__ cursor,
                                                 int* __restrict__ elist) {
  int e = blockIdx.x * 256 + threadIdx.x;
  if (e < NEDGE) {
    int p = atomicAdd(&cursor[src[e]], 1);
    elist[p] = e;
  }
}

// agg[row][t] = sum over edges of row of relu(path_feats[e][t]) -- no atomics
__global__ __launch_bounds__(256) void k_gather(const float* __restrict__ pf,
                                                const int* __restrict__ offsets,
                                                const int* __restrict__ elist,
                                                float* __restrict__ agg) {
  const int row = blockIdx.x;
  const int t = threadIdx.x;
  if (t >= EDIM) return;
  const int beg = offsets[row];
  const int end = offsets[row + 1];
  float acc0 = 0.f, acc1 = 0.f;
  int e = beg;
  for (; e + 1 < end; e += 2) {
    int e0 = elist[e];
    int e1 = elist[e + 1];
    float v0 = pf[(size_t)e0 * EDIM + t];
    float v1 = pf[(size_t)e1 * EDIM + t];
    acc0 += fmaxf(v0, 0.f);
    acc1 += fmaxf(v1, 0.f);
  }
  if (e < end) {
    int e0 = elist[e];
    acc0 += fmaxf(pf[(size_t)e0 * EDIM + t], 0.f);
  }
  agg[(size_t)row * EDIM + t] = acc0 + acc1;
}

// ---------------------------------------------------------------- fp32 GEMM
// C[M,N] = f(A'[M,K] @ B[K,N]); BM=BN=128, BK=8, 256 threads, 8x8 per thread.
// ATR: 0=none, 1=BN+relu on A-load (z = relu(g*(a-mean)*rstd + b))
// EPI: 0=store; 1=C=Cin+acc+bias, column stats; 2=relu(acc+bias);
//      3=acc+bias(+bias2); 4=acc+gatherTab[srcids[m]][:], column stats
template <int ATR, int EPI>
__global__ __launch_bounds__(256)
void gemm_k(const float* __restrict__ A, const float* __restrict__ B,
            float* __restrict__ C, int M, int K, int N,
            const float* __restrict__ bn_g, const float* __restrict__ bn_b,
            const float* __restrict__ bn_mean, const float* __restrict__ bn_rstd,
            const float* __restrict__ bias, const float* __restrict__ bias2,
            const float* __restrict__ Cin,
            const int* __restrict__ srcids, const float* __restrict__ gatherTab,
            float* __restrict__ colsum, float* __restrict__ colsumsq) {
  __shared__ float As[8][128];   // [k][m]
  __shared__ float Bs[8][128];   // [k][n]
  __shared__ float red[16][128];
  constexpr bool STATS = (EPI == 1 || EPI == 4);

  const int tid = threadIdx.x;
  const int tx = tid & 15;       // col group (8 cols)
  const int ty = tid >> 4;       // row group (8 rows)
  const int bm = blockIdx.x * 128;
  const int bn = blockIdx.y * 128;

  float acc[8][8];
#pragma unroll
  for (int i = 0; i < 8; ++i)
#pragma unroll
    for (int j = 0; j < 8; ++j) acc[i][j] = 0.f;

  for (int k0 = 0; k0 < K; k0 += 8) {
    // stage A tile (transposed into [k][m])
    {
      int r = tid >> 1;
      int cq = (tid & 1) << 2;
      float4 v = make_float4(0.f, 0.f, 0.f, 0.f);
      int row = bm + r;
      if (row < M) {
        const float* ap = A + (size_t)row * K + k0 + cq;
        if (k0 + cq + 4 <= K) {
          v = *(const float4*)ap;
        } else {
          float tmp[4] = {0.f, 0.f, 0.f, 0.f};
          for (int q = 0; q < 4; ++q)
            if (k0 + cq + q < K) tmp[q] = ap[q];
          v = make_float4(tmp[0], tmp[1], tmp[2], tmp[3]);
        }
      }
      if constexpr (ATR == 1) {
        float vv[4] = {v.x, v.y, v.z, v.w};
#pragma unroll
        for (int q = 0; q < 4; ++q) {
          int k = k0 + cq + q;
          if (k < K) {
            vv[q] = fmaxf(fmaf(bn_g[k], (vv[q] - bn_mean[k]) * bn_rstd[k], bn_b[k]), 0.f);
          } else {
            vv[q] = 0.f;
          }
        }
        v = make_float4(vv[0], vv[1], vv[2], vv[3]);
      }
      As[cq + 0][r] = v.x;
      As[cq + 1][r] = v.y;
      As[cq + 2][r] = v.z;
      As[cq + 3][r] = v.w;
    }
    // stage B tile
    {
      int r = tid >> 5;
      int c = (tid & 31) << 2;
      float4 v = make_float4(0.f, 0.f, 0.f, 0.f);
      int kk = k0 + r;
      if (kk < K) v = *(const float4*)(B + (size_t)kk * N + bn + c);
      *(float4*)&Bs[r][c] = v;
    }
    __syncthreads();
#pragma unroll
    for (int kk = 0; kk < 8; ++kk) {
      const float4 a0 = *(const float4*)&As[kk][ty * 8];
      const float4 a1 = *(const float4*)&As[kk][ty * 8 + 4];
      const float4 b0 = *(const float4*)&Bs[kk][tx * 8];
      const float4 b1 = *(const float4*)&Bs[kk][tx * 8 + 4];
      const float av[8] = {a0.x, a0.y, a0.z, a0.w, a1.x, a1.y, a1.z, a1.w};
      const float bv[8] = {b0.x, b0.y, b0.z, b0.w, b1.x, b1.y, b1.z, b1.w};
#pragma unroll
      for (int i = 0; i < 8; ++i)
#pragma unroll
        for (int j = 0; j < 8; ++j) acc[i][j] = fmaf(av[i], bv[j], acc[i][j]);
    }
    __syncthreads();
  }

  // epilogue
  const int nb = bn + tx * 8;
  float colS[8], colQ[8];
  if constexpr (STATS) {
#pragma unroll
    for (int j = 0; j < 8; ++j) { colS[j] = 0.f; colQ[j] = 0.f; }
  }
#pragma unroll
  for (int i = 0; i < 8; ++i) {
    int m = bm + ty * 8 + i;
    if (m < M) {
      float outv[8];
#pragma unroll
      for (int j = 0; j < 8; ++j) outv[j] = acc[i][j];
      if constexpr (EPI == 1) {
        const float* crow = Cin + (size_t)m * N + nb;
#pragma unroll
        for (int j = 0; j < 8; ++j) outv[j] += crow[j] + bias[nb + j];
      } else if constexpr (EPI == 2) {
#pragma unroll
        for (int j = 0; j < 8; ++j) outv[j] = fmaxf(outv[j] + bias[nb + j], 0.f);
      } else if constexpr (EPI == 3) {
#pragma unroll
        for (int j = 0; j < 8; ++j) {
          float bb = bias[nb + j];
          if (bias2) bb += bias2[nb + j];
          outv[j] += bb;
        }
      } else if constexpr (EPI == 4) {
        int s = srcids[m];
        const float* g = gatherTab + (size_t)s * N + nb;
#pragma unroll
        for (int j = 0; j < 8; ++j) outv[j] += g[j];
      }
      float* crow = C + (size_t)m * N + nb;
      *(float4*)crow = make_float4(outv[0], outv[1], outv[2], outv[3]);
      *(float4*)(crow + 4) = make_float4(outv[4], outv[5], outv[6], outv[7]);
      if constexpr (STATS) {
#pragma unroll
        for (int j = 0; j < 8; ++j) { colS[j] += outv[j]; colQ[j] += outv[j] * outv[j]; }
      }
    }
  }
  if constexpr (STATS) {
    *(float4*)&red[ty][tx * 8] = make_float4(colS[0], colS[1], colS[2], colS[3]);
    *(float4*)&red[ty][tx * 8 + 4] = make_float4(colS[4], colS[5], colS[6], colS[7]);
    __syncthreads();
    if (tid < 128) {
      float s = 0.f;
#pragma unroll
      for (int t = 0; t < 16; ++t) s += red[t][tid];
      atomicAdd(colsum + bn + tid, s);
    }
    __syncthreads();
    *(float4*)&red[ty][tx * 8] = make_float4(colQ[0], colQ[1], colQ[2], colQ[3]);
    *(float4*)&red[ty][tx * 8 + 4] = make_float4(colQ[4], colQ[5], colQ[6], colQ[7]);
    __syncthreads();
    if (tid < 128) {
      float s = 0.f;
#pragma unroll
      for (int t = 0; t < 16; ++t) s += red[t][tid];
      atomicAdd(colsumsq + bn + tid, s);
    }
  }
}

// ---------------------------------------------------------------- stat finalize
__global__ void k_finT(float* __restrict__ st) {
  int j = threadIdx.x;  // 384
  float mean = st[j] * (1.0f / NSRC);
  float var = st[384 + j] * (1.0f / NSRC) - mean * mean;
  st[768 + j] = mean;
  st[1152 + j] = rsqrtf(var + 1e-5f);
}

__global__ void k_finP(float* __restrict__ st, const float* __restrict__ g,
                       const float* __restrict__ b) {
  int j = threadIdx.x;  // 128
  float mean = st[j] * (1.0f / NEDGE);
  float var = st[128 + j] * (1.0f / NEDGE) - mean * mean;
  float rstd = rsqrtf(var + 1e-5f);
  float a = g[j] * rstd;
  st[256 + j] = a;              // scale
  st[384 + j] = b[j] - a * mean; // shift
}

// ---------------------------------------------------------------- scoring
// scores[e] = sum_j relu(a[j]*hpath[e][j] + c[j]) * w[j]; 16 lanes per row
__global__ __launch_bounds__(256) void k_score(const float* __restrict__ hpath,
                                               const float* __restrict__ aP,
                                               const float* __restrict__ cP,
                                               const float* __restrict__ w,
                                               float* __restrict__ scores) {
  const int row = blockIdx.x * 16 + (threadIdx.x >> 4);
  const int cg = threadIdx.x & 15;
  const float* hp = hpath + (size_t)row * 128 + cg * 8;
  const float4 x0 = *(const float4*)hp;
  const float4 x1 = *(const float4*)(hp + 4);
  const float xs[8] = {x0.x, x0.y, x0.z, x0.w, x1.x, x1.y, x1.z, x1.w};
  float part = 0.f;
#pragma unroll
  for (int q = 0; q < 8; ++q) {
    int j = cg * 8 + q;
    part += fmaxf(fmaf(aP[j], xs[q], cP[j]), 0.f) * w[j];
  }
#pragma unroll
  for (int o = 8; o >= 1; o >>= 1) part += __shfl_xor(part, o, 16);
  if (cg == 0) scores[row] = part;
}

// ---------------------------------------------------------------- top-k
__global__ __launch_bounds__(256) void k_top1(const float* __restrict__ scores,
                                              KV* __restrict__ cand) {
  KV t[TOPN];
#pragma unroll
  for (int q = 0; q < TOPN; ++q) { t[q].v = -INFINITY; t[q].i = 2147483647; }
  for (int e = blockIdx.x * 256 + threadIdx.x; e < NEDGE; e += 256 * 256) {
    float v = scores[e];
    if (v > t[TOPN - 1].v) {      // strict: equal keeps earlier (smaller) index
      t[TOPN - 1].v = v;
      t[TOPN - 1].i = e;
#pragma unroll
      for (int q = TOPN - 1; q > 0; --q) {
        if (t[q].v > t[q - 1].v) { KV tmp = t[q - 1]; t[q - 1] = t[q]; t[q] = tmp; }
      }
    }
  }
  __shared__ KV sh[128][TOPN];
  int tid = threadIdx.x;
  for (int s = 128; s >= 1; s >>= 1) {
    if (tid >= s && tid < 2 * s) {
#pragma unroll
      for (int q = 0; q < TOPN; ++q) sh[tid - s][q] = t[q];
    }
    __syncthreads();
    if (tid < s) kv_merge(t, sh[tid]);
    __syncthreads();
  }
  if (tid == 0) {
#pragma unroll
    for (int q = 0; q < TOPN; ++q) cand[blockIdx.x * TOPN + q] = t[q];
  }
}

__global__ __launch_bounds__(256) void k_top2(const KV* __restrict__ cand,
                                              float* __restrict__ outTail) {
  int tid = threadIdx.x;
  KV t[TOPN];
#pragma unroll
  for (int q = 0; q < TOPN; ++q) t[q] = cand[tid * TOPN + q];
  __shared__ KV sh[128][TOPN];
  for (int s = 128; s >= 1; s >>= 1) {
    if (tid >= s && tid < 2 * s) {
#pragma unroll
      for (int q = 0; q < TOPN; ++q) sh[tid - s][q] = t[q];
    }
    __syncthreads();
    if (tid < s) kv_merge(t, sh[tid]);
    __syncthreads();
  }
  if (tid == 0) {
#pragma unroll
    for (int q = 0; q < TOPN; ++q) {
      outTail[q] = t[q].v;
      outTail[TOPN + q] = (float)t[q].i;   // harness reads flat fp32
    }
  }
}

// ---------------------------------------------------------------- launch
extern "C" void kernel_launch(void* const* d_in, const int* in_sizes, int n_in,
                              void* d_out, int out_size, void* d_ws, size_t ws_size,
                              hipStream_t stream) {
  const float* paths_srcs = (const float*)d_in[0];
  const float* path_feats = (const float*)d_in[1];
  const int* src_ids = (const int*)d_in[2];
  const float* cew = (const float*)d_in[3];
  const float* ceb = (const float*)d_in[4];
  const float* cw1 = (const float*)d_in[5];
  const float* bng = (const float*)d_in[6];
  const float* bnbt = (const float*)d_in[7];
  const float* cw2 = (const float*)d_in[8];
  const float* l1w = (const float*)d_in[9];
  const float* l1b = (const float*)d_in[10];
  const float* l2w = (const float*)d_in[11];
  const float* l2b = (const float*)d_in[12];
  const float* psw = (const float*)d_in[13];
  const float* psb = (const float*)d_in[14];
  const float* ptw = (const float*)d_in[15];
  const float* ptb = (const float*)d_in[16];
  const float* pbg = (const float*)d_in[17];
  const float* pbb = (const float*)d_in[18];
  const float* scw = (const float*)d_in[19];
  float* out = (float*)d_out;
  float* ws = (float*)d_ws;

  // workspace layout (floats)
  float* w1cat = ws;                        // 49152
  float* wew1cat = w1cat + 49152;           // 90624
  float* bprime = wew1cat + 90624;          // 512
  float* m1 = bprime + 512;                 // 49152
  float* statsT = m1 + 49152;               // 1536: sum|sumsq|mean|rstd
  float* statsP = statsT + 1536;            // 512:  sum|sumsq|a|c
  float* agg = statsP + 512;                // 2360000
  float* T = agg + 2360000;                 // 3840000
  float* H1 = T + 3840000;                  // 1280000
  float* pre_src = H1 + 1280000;            // 1280000
  float* scores = pre_src + 1280000;        // 320000
  KV* cand = (KV*)(scores + 320000);        // 1536 KV = 3072 floats
  float* hpath = scores + 320000 + 3072;    // 40960000
  // CSR arrays overlap the hpath region: live only before the GEMM phase,
  // hpath is written long after k_gather consumed them.
  int* counts = (int*)hpath;                // 10000
  int* offsets = counts + 10000;            // 10001
  int* cursor = offsets + 10001;            // 10000
  int* elist = cursor + 10000;              // 320000   (total 350011 << 40.96M)
  const size_t needed = (size_t)(49152 + 90624 + 512 + 49152 + 1536 + 512 + 2360000 +
                                 3840000 + 1280000 + 1280000 + 320000 + 3072 +
                                 40960000) * 4;
  if (ws_size < needed) {
    k_sentinel<<<1, 64, 0, stream>>>(out);  // distinguishable failure: out[0]=1e9
    return;
  }

  const float* np = nullptr;

  // weight prep
  k_prep_w1cat<<<192, 256, 0, stream>>>(cw1, w1cat);
  k_prep_wew1<<<708, 128, 0, stream>>>(cew, cw1, wew1cat);
  k_prep_bprime<<<3, 128, 0, stream>>>(ceb, cw1, bprime);
  k_prep_m1<<<384, 128, 0, stream>>>(cw2, l1w, m1);

  // zero stat accumulators + CSR counts (ws is poisoned 0xAA before every call)
  k_zero<<<8, 256, 0, stream>>>(statsT, 2048);  // statsT(1536)+statsP(512) contiguous
  k_zero<<<(10000 + 255) / 256, 256, 0, stream>>>((float*)counts, 10000);

  // CSR build + gather-based segment sum (no atomics in the heavy phase)
  k_hist<<<(NEDGE + 255) / 256, 256, 0, stream>>>(src_ids, counts);
  k_scan<<<1, 256, 0, stream>>>(counts, offsets, cursor);
  k_scatter<<<(NEDGE + 255) / 256, 256, 0, stream>>>(src_ids, cursor, elist);
  k_gather<<<NSRC, 256, 0, stream>>>(path_feats, offsets, elist, agg);

  // T = paths_srcs @ W1cat                       [10000,384]
  gemm_k<0, 0><<<dim3(79, 3), 256, 0, stream>>>(paths_srcs, w1cat, T, NSRC, 128, 384,
                                                np, np, np, np, np, np, np, nullptr, np,
                                                nullptr, nullptr);
  // T += agg @ WeW1cat + bprime, column stats
  gemm_k<0, 1><<<dim3(79, 3), 256, 0, stream>>>(agg, wew1cat, T, NSRC, EDIM, 384,
                                                np, np, np, np, bprime, np, T, nullptr,
                                                np, statsT, statsT + 384);
  k_finT<<<1, 384, 0, stream>>>(statsT);
  // H1 = relu(relu(BN(T)) @ M1 + lin1_b)         [10000,128]
  gemm_k<1, 2><<<dim3(79, 1), 256, 0, stream>>>(T, m1, H1, NSRC, 384, 128,
                                                bng, bnbt, statsT + 768, statsT + 1152,
                                                l1b, np, np, nullptr, np, nullptr, nullptr);
  // node_emb = H1 @ lin2_W + lin2_b  -> d_out
  gemm_k<0, 3><<<dim3(79, 1), 256, 0, stream>>>(H1, l2w, out, NSRC, 128, 128,
                                                np, np, np, np, l2b, np, np, nullptr, np,
                                                nullptr, nullptr);
  // pre_src = node_emb @ pe_src_W + (pe_src_b + pe_tgt_b)
  gemm_k<0, 3><<<dim3(79, 1), 256, 0, stream>>>(out, psw, pre_src, NSRC, 128, 128,
                                                np, np, np, np, psb, ptb, np, nullptr, np,
                                                nullptr, nullptr);
  // hpath = path_feats @ pe_tgt_W + pre_src[src_ids], column stats  [320000,128]
  gemm_k<0, 4><<<dim3(2500, 1), 256, 0, stream>>>(path_feats, ptw, hpath, NEDGE, EDIM, 128,
                                                  np, np, np, np, np, np, np, src_ids,
                                                  pre_src, statsP, statsP + 128);
  k_finP<<<1, 128, 0, stream>>>(statsP, pbg, pbb);
  // scores + top-6
  k_score<<<NEDGE / 16, 256, 0, stream>>>(hpath, statsP + 256, statsP + 384, scw, scores);
  k_top1<<<256, 256, 0, stream>>>(scores, cand);
  k_top2<<<1, 256, 0, stream>>>(cand, out + (size_t)NSRC * 128);
}

// Round 3
// 1072.479 us; speedup vs baseline: 1.8030x; 1.0804x over previous
//
#include <hip/hip_runtime.h>
#include <math.h>

#define NSRC 10000
#define NEDGE 320000
#define EDIM 236
#define TOPN 6

typedef __attribute__((ext_vector_type(8))) short short8;
typedef __attribute__((ext_vector_type(4))) float floatx4;

// ---------------------------------------------------------------- bf16 split
__device__ __forceinline__ unsigned short bf16_rne(float x) {
  union { float f; unsigned int u; } c; c.f = x;
  unsigned int r = (c.u + 0x7FFFu + ((c.u >> 16) & 1u)) >> 16;
  return (unsigned short)r;
}
__device__ __forceinline__ float bf16_to_f(unsigned short h) {
  union { unsigned int u; float f; } c; c.u = ((unsigned int)h) << 16;
  return c.f;
}
__device__ __forceinline__ void split_f32(float x, unsigned short& h, unsigned short& l) {
  h = bf16_rne(x);
  l = bf16_rne(x - bf16_to_f(h));
}

// ---------------------------------------------------------------- top-k utils
struct KV { float v; int i; };

__device__ __forceinline__ bool kv_better(const KV a, const KV b) {
  return (a.v > b.v) || (a.v == b.v && a.i < b.i);
}

__device__ __forceinline__ void kv_merge(KV d[TOPN], const KV o[TOPN]) {
  KV r[TOPN];
  int ia = 0, ib = 0;
#pragma unroll
  for (int q = 0; q < TOPN; ++q) {
    bool takeA;
    if (ia >= TOPN) takeA = false;
    else if (ib >= TOPN) takeA = true;
    else takeA = kv_better(d[ia], o[ib]);
    r[q] = takeA ? d[ia] : o[ib];
    if (takeA) ia++; else ib++;
  }
#pragma unroll
  for (int q = 0; q < TOPN; ++q) d[q] = r[q];
}

// ---------------------------------------------------------------- small utils
__global__ void k_zero(float* __restrict__ p, int n) {
  int i = blockIdx.x * 256 + threadIdx.x;
  if (i < n) p[i] = 0.f;
}

__global__ void k_sentinel(float* __restrict__ out) {
  if (threadIdx.x == 0) out[0] = 1.0e9f;
}

// ---------------------------------------------------------------- weight prep
__global__ void k_prep_w1cat(const float* __restrict__ cw1, float* __restrict__ w1cat) {
  int gid = blockIdx.x * 256 + threadIdx.x;
  if (gid >= 3 * 128 * 128) return;
  int i = gid >> 14;
  int m = (gid >> 7) & 127;
  int j = gid & 127;
  w1cat[m * 384 + i * 128 + j] = cw1[gid];
}

__global__ void k_prep_wew1(const float* __restrict__ cew, const float* __restrict__ cw1,
                            float* __restrict__ wew1cat) {
  int b = blockIdx.x;            // 0..707 = i*236+k
  int i = b / EDIM;
  int k = b - i * EDIM;
  int j = threadIdx.x;           // 0..127
  const float* we = cew + ((size_t)i * EDIM + k) * 128;
  const float* w1 = cw1 + (size_t)i * 16384;
  float acc = 0.f;
  for (int m = 0; m < 128; ++m) acc = fmaf(we[m], w1[m * 128 + j], acc);
  wew1cat[k * 384 + i * 128 + j] = acc;
}

__global__ void k_prep_bprime(const float* __restrict__ ceb, const float* __restrict__ cw1,
                              float* __restrict__ bprime) {
  int i = blockIdx.x;            // 0..2
  int j = threadIdx.x;           // 0..127
  const float* be = ceb + i * 128;
  const float* w1 = cw1 + (size_t)i * 16384;
  float acc = 0.f;
  for (int m = 0; m < 128; ++m) acc = fmaf(be[m], w1[m * 128 + j], acc);
  bprime[i * 128 + j] = acc;
}

__global__ void k_prep_m1(const float* __restrict__ cw2, const float* __restrict__ l1w,
                          float* __restrict__ m1) {
  int b = blockIdx.x;            // 0..383 = i*128+r
  int i = b >> 7;
  int r = b & 127;
  int j = threadIdx.x;           // 0..127
  const float* w2 = cw2 + (size_t)i * 16384 + r * 128;
  float acc = 0.f;
  for (int c = 0; c < 128; ++c) acc = fmaf(w2[c], l1w[((size_t)i * 128 + c) * 128 + j], acc);
  m1[b * 128 + j] = acc;
}

// pre-split pe_tgt_W [236][128] fp32 -> Bh/Bl [128][256] bf16 (n-major, zero-padded)
__global__ void k_prep_bsplit(const float* __restrict__ ptw,
                              unsigned short* __restrict__ Bh,
                              unsigned short* __restrict__ Bl) {
  int n = blockIdx.x;            // 0..127
  int k = threadIdx.x;           // 0..255
  float v = (k < EDIM) ? ptw[(size_t)k * 128 + n] : 0.f;
  unsigned short h, l;
  split_f32(v, h, l);
  Bh[n * 256 + k] = h;
  Bl[n * 256 + k] = l;
}

// ---------------------------------------------------------------- CSR build
__global__ __launch_bounds__(256) void k_hist(const int* __restrict__ src,
                                              int* __restrict__ counts) {
  int e = blockIdx.x * 256 + threadIdx.x;
  if (e < NEDGE) atomicAdd(&counts[src[e]], 1);
}

__global__ __launch_bounds__(256) void k_scan(const int* __restrict__ counts,
                                              int* __restrict__ offsets,
                                              int* __restrict__ cursor) {
  __shared__ int part[256];
  const int t = threadIdx.x;
  const int base = t * 40;
  int s = 0;
  for (int k = 0; k < 40; ++k) {
    int i = base + k;
    if (i < NSRC) s += counts[i];
  }
  part[t] = s;
  __syncthreads();
  for (int off = 1; off < 256; off <<= 1) {
    int v = (t >= off) ? part[t - off] : 0;
    __syncthreads();
    part[t] += v;
    __syncthreads();
  }
  int run = (t == 0) ? 0 : part[t - 1];
  for (int k = 0; k < 40; ++k) {
    int i = base + k;
    if (i < NSRC) {
      offsets[i] = run;
      cursor[i] = run;
      run += counts[i];
    }
  }
  if (t == 255) offsets[NSRC] = run;
}

__global__ __launch_bounds__(256) void k_scatter(const int* __restrict__ src,
                                                 int* __restrict__ cursor,
                                                 int* __restrict__ elist) {
  int e = blockIdx.x * 256 + threadIdx.x;
  if (e < NEDGE) {
    int p = atomicAdd(&cursor[src[e]], 1);
    elist[p] = e;
  }
}

__global__ __launch_bounds__(256) void k_gather(const float* __restrict__ pf,
                                                const int* __restrict__ offsets,
                                                const int* __restrict__ elist,
                                                float* __restrict__ agg) {
  const int row = blockIdx.x;
  const int t = threadIdx.x;
  if (t >= EDIM) return;
  const int beg = offsets[row];
  const int end = offsets[row + 1];
  float acc0 = 0.f, acc1 = 0.f;
  int e = beg;
  for (; e + 1 < end; e += 2) {
    int e0 = elist[e];
    int e1 = elist[e + 1];
    float v0 = pf[(size_t)e0 * EDIM + t];
    float v1 = pf[(size_t)e1 * EDIM + t];
    acc0 += fmaxf(v0, 0.f);
    acc1 += fmaxf(v1, 0.f);
  }
  if (e < end) {
    int e0 = elist[e];
    acc0 += fmaxf(pf[(size_t)e0 * EDIM + t], 0.f);
  }
  agg[(size_t)row * EDIM + t] = acc0 + acc1;
}

// ---------------------------------------------------------------- fp32 GEMM (small node GEMMs)
template <int ATR, int EPI>
__global__ __launch_bounds__(256)
void gemm_k(const float* __restrict__ A, const float* __restrict__ B,
            float* __restrict__ C, int M, int K, int N,
            const float* __restrict__ bn_g, const float* __restrict__ bn_b,
            const float* __restrict__ bn_mean, const float* __restrict__ bn_rstd,
            const float* __restrict__ bias, const float* __restrict__ bias2,
            const float* __restrict__ Cin,
            const int* __restrict__ srcids, const float* __restrict__ gatherTab,
            float* __restrict__ colsum, float* __restrict__ colsumsq) {
  __shared__ float As[8][128];   // [k][m]
  __shared__ float Bs[8][128];   // [k][n]
  __shared__ float red[16][128];
  constexpr bool STATS = (EPI == 1 || EPI == 4);

  const int tid = threadIdx.x;
  const int tx = tid & 15;
  const int ty = tid >> 4;
  const int bm = blockIdx.x * 128;
  const int bn = blockIdx.y * 128;

  float acc[8][8];
#pragma unroll
  for (int i = 0; i < 8; ++i)
#pragma unroll
    for (int j = 0; j < 8; ++j) acc[i][j] = 0.f;

  for (int k0 = 0; k0 < K; k0 += 8) {
    {
      int r = tid >> 1;
      int cq = (tid & 1) << 2;
      float4 v = make_float4(0.f, 0.f, 0.f, 0.f);
      int row = bm + r;
      if (row < M) {
        const float* ap = A + (size_t)row * K + k0 + cq;
        if (k0 + cq + 4 <= K) {
          v = *(const float4*)ap;
        } else {
          float tmp[4] = {0.f, 0.f, 0.f, 0.f};
          for (int q = 0; q < 4; ++q)
            if (k0 + cq + q < K) tmp[q] = ap[q];
          v = make_float4(tmp[0], tmp[1], tmp[2], tmp[3]);
        }
      }
      if constexpr (ATR == 1) {
        float vv[4] = {v.x, v.y, v.z, v.w};
#pragma unroll
        for (int q = 0; q < 4; ++q) {
          int k = k0 + cq + q;
          if (k < K) {
            vv[q] = fmaxf(fmaf(bn_g[k], (vv[q] - bn_mean[k]) * bn_rstd[k], bn_b[k]), 0.f);
          } else {
            vv[q] = 0.f;
          }
        }
        v = make_float4(vv[0], vv[1], vv[2], vv[3]);
      }
      As[cq + 0][r] = v.x;
      As[cq + 1][r] = v.y;
      As[cq + 2][r] = v.z;
      As[cq + 3][r] = v.w;
    }
    {
      int r = tid >> 5;
      int c = (tid & 31) << 2;
      float4 v = make_float4(0.f, 0.f, 0.f, 0.f);
      int kk = k0 + r;
      if (kk < K) v = *(const float4*)(B + (size_t)kk * N + bn + c);
      *(float4*)&Bs[r][c] = v;
    }
    __syncthreads();
#pragma unroll
    for (int kk = 0; kk < 8; ++kk) {
      const float4 a0 = *(const float4*)&As[kk][ty * 8];
      const float4 a1 = *(const float4*)&As[kk][ty * 8 + 4];
      const float4 b0 = *(const float4*)&Bs[kk][tx * 8];
      const float4 b1 = *(const float4*)&Bs[kk][tx * 8 + 4];
      const float av[8] = {a0.x, a0.y, a0.z, a0.w, a1.x, a1.y, a1.z, a1.w};
      const float bv[8] = {b0.x, b0.y, b0.z, b0.w, b1.x, b1.y, b1.z, b1.w};
#pragma unroll
      for (int i = 0; i < 8; ++i)
#pragma unroll
        for (int j = 0; j < 8; ++j) acc[i][j] = fmaf(av[i], bv[j], acc[i][j]);
    }
    __syncthreads();
  }

  const int nb = bn + tx * 8;
  float colS[8], colQ[8];
  if constexpr (STATS) {
#pragma unroll
    for (int j = 0; j < 8; ++j) { colS[j] = 0.f; colQ[j] = 0.f; }
  }
#pragma unroll
  for (int i = 0; i < 8; ++i) {
    int m = bm + ty * 8 + i;
    if (m < M) {
      float outv[8];
#pragma unroll
      for (int j = 0; j < 8; ++j) outv[j] = acc[i][j];
      if constexpr (EPI == 1) {
        const float* crow = Cin + (size_t)m * N + nb;
#pragma unroll
        for (int j = 0; j < 8; ++j) outv[j] += crow[j] + bias[nb + j];
      } else if constexpr (EPI == 2) {
#pragma unroll
        for (int j = 0; j < 8; ++j) outv[j] = fmaxf(outv[j] + bias[nb + j], 0.f);
      } else if constexpr (EPI == 3) {
#pragma unroll
        for (int j = 0; j < 8; ++j) {
          float bb = bias[nb + j];
          if (bias2) bb += bias2[nb + j];
          outv[j] += bb;
        }
      } else if constexpr (EPI == 4) {
        int s = srcids[m];
        const float* g = gatherTab + (size_t)s * N + nb;
#pragma unroll
        for (int j = 0; j < 8; ++j) outv[j] += g[j];
      }
      float* crow = C + (size_t)m * N + nb;
      *(float4*)crow = make_float4(outv[0], outv[1], outv[2], outv[3]);
      *(float4*)(crow + 4) = make_float4(outv[4], outv[5], outv[6], outv[7]);
      if constexpr (STATS) {
#pragma unroll
        for (int j = 0; j < 8; ++j) { colS[j] += outv[j]; colQ[j] += outv[j] * outv[j]; }
      }
    }
  }
  if constexpr (STATS) {
    *(float4*)&red[ty][tx * 8] = make_float4(colS[0], colS[1], colS[2], colS[3]);
    *(float4*)&red[ty][tx * 8 + 4] = make_float4(colS[4], colS[5], colS[6], colS[7]);
    __syncthreads();
    if (tid < 128) {
      float s = 0.f;
#pragma unroll
      for (int t = 0; t < 16; ++t) s += red[t][tid];
      atomicAdd(colsum + bn + tid, s);
    }
    __syncthreads();
    *(float4*)&red[ty][tx * 8] = make_float4(colQ[0], colQ[1], colQ[2], colQ[3]);
    *(float4*)&red[ty][tx * 8 + 4] = make_float4(colQ[4], colQ[5], colQ[6], colQ[7]);
    __syncthreads();
    if (tid < 128) {
      float s = 0.f;
#pragma unroll
      for (int t = 0; t < 16; ++t) s += red[t][tid];
      atomicAdd(colsumsq + bn + tid, s);
    }
  }
}

// ---------------------------------------------------------------- big GEMM: split-bf16 MFMA
// hpath[M=320000,128] = path_feats[M,236] @ pe_tgt_W[236,128] + pre_src[srcids[m]][:]
// a*b ~= ah*bh + ah*bl + al*bh  (error ~2^-16 rel). Accumulate column sum/sumsq.
__global__ __launch_bounds__(256)
void k_hgemm(const float* __restrict__ A, const unsigned short* __restrict__ Bh,
             const unsigned short* __restrict__ Bl, const int* __restrict__ srcids,
             const float* __restrict__ pre_src, float* __restrict__ hpath,
             float* __restrict__ colsum, float* __restrict__ colsumsq) {
  // pitch 40 bf16 = 80 B = 20 banks -> 2-way max conflict on b128 fragment reads (free)
  __shared__ __align__(16) unsigned short Ah[128][40];
  __shared__ __align__(16) unsigned short Al[128][40];
  __shared__ __align__(16) unsigned short Bhs[128][40];
  __shared__ __align__(16) unsigned short Bls[128][40];
  __shared__ float redS[4][128];
  __shared__ float redQ[4][128];

  const int tid = threadIdx.x;
  const int wave = tid >> 6;
  const int lane = tid & 63;
  const int am = lane & 15;      // fragment row/col within 16
  const int aq = lane >> 4;      // k-quad
  const int bm = blockIdx.x * 128;

  floatx4 acc[2][8];
#pragma unroll
  for (int mt = 0; mt < 2; ++mt)
#pragma unroll
    for (int nt = 0; nt < 8; ++nt) acc[mt][nt] = (floatx4){0.f, 0.f, 0.f, 0.f};

  const int rowS = tid >> 1;          // staging row (0..127)
  const int kq = (tid & 1) * 16;      // staging k offset (0 or 16)

  for (int c = 0; c < 8; ++c) {
    const int k0 = c * 32;
    // ---- stage A (fp32 -> hi/lo bf16) ----
    {
      const float* ap = A + (size_t)(bm + rowS) * EDIM + k0 + kq;
      short8 vh0, vl0, vh1, vl1;
#pragma unroll
      for (int i = 0; i < 4; ++i) {
        float4 v = make_float4(0.f, 0.f, 0.f, 0.f);
        if (k0 + kq + i * 4 + 4 <= EDIM) v = *(const float4*)(ap + i * 4);
        unsigned short h0, l0, h1, l1, h2, l2, h3, l3;
        split_f32(v.x, h0, l0);
        split_f32(v.y, h1, l1);
        split_f32(v.z, h2, l2);
        split_f32(v.w, h3, l3);
        if (i < 2) {
          vh0[i * 4 + 0] = (short)h0; vl0[i * 4 + 0] = (short)l0;
          vh0[i * 4 + 1] = (short)h1; vl0[i * 4 + 1] = (short)l1;
          vh0[i * 4 + 2] = (short)h2; vl0[i * 4 + 2] = (short)l2;
          vh0[i * 4 + 3] = (short)h3; vl0[i * 4 + 3] = (short)l3;
        } else {
          int q = (i - 2) * 4;
          vh1[q + 0] = (short)h0; vl1[q + 0] = (short)l0;
          vh1[q + 1] = (short)h1; vl1[q + 1] = (short)l1;
          vh1[q + 2] = (short)h2; vl1[q + 2] = (short)l2;
          vh1[q + 3] = (short)h3; vl1[q + 3] = (short)l3;
        }
      }
      *(short8*)&Ah[rowS][kq] = vh0;
      *(short8*)&Ah[rowS][kq + 8] = vh1;
      *(short8*)&Al[rowS][kq] = vl0;
      *(short8*)&Al[rowS][kq + 8] = vl1;
    }
    // ---- stage B (pre-split bf16, straight copy) ----
    {
      const unsigned short* bhp = Bh + (size_t)rowS * 256 + k0 + kq;
      const unsigned short* blp = Bl + (size_t)rowS * 256 + k0 + kq;
      *(short8*)&Bhs[rowS][kq] = *(const short8*)bhp;
      *(short8*)&Bhs[rowS][kq + 8] = *(const short8*)(bhp + 8);
      *(short8*)&Bls[rowS][kq] = *(const short8*)blp;
      *(short8*)&Bls[rowS][kq + 8] = *(const short8*)(blp + 8);
    }
    __syncthreads();
    // ---- MFMA ----
    {
      const int m0 = wave * 32 + am;
      const short8 ah0 = *(const short8*)&Ah[m0][aq * 8];
      const short8 al0 = *(const short8*)&Al[m0][aq * 8];
      const short8 ah1 = *(const short8*)&Ah[m0 + 16][aq * 8];
      const short8 al1 = *(const short8*)&Al[m0 + 16][aq * 8];
#pragma unroll
      for (int nt = 0; nt < 8; ++nt) {
        const short8 bh = *(const short8*)&Bhs[nt * 16 + am][aq * 8];
        const short8 bl = *(const short8*)&Bls[nt * 16 + am][aq * 8];
        acc[0][nt] = __builtin_amdgcn_mfma_f32_16x16x32_bf16(ah0, bl, acc[0][nt], 0, 0, 0);
        acc[0][nt] = __builtin_amdgcn_mfma_f32_16x16x32_bf16(al0, bh, acc[0][nt], 0, 0, 0);
        acc[0][nt] = __builtin_amdgcn_mfma_f32_16x16x32_bf16(ah0, bh, acc[0][nt], 0, 0, 0);
        acc[1][nt] = __builtin_amdgcn_mfma_f32_16x16x32_bf16(ah1, bl, acc[1][nt], 0, 0, 0);
        acc[1][nt] = __builtin_amdgcn_mfma_f32_16x16x32_bf16(al1, bh, acc[1][nt], 0, 0, 0);
        acc[1][nt] = __builtin_amdgcn_mfma_f32_16x16x32_bf16(ah1, bh, acc[1][nt], 0, 0, 0);
      }
    }
    __syncthreads();
  }

  // ---- epilogue: + pre_src[srcids[m]], store, column stats ----
  float colS[8], colQ[8];
#pragma unroll
  for (int nt = 0; nt < 8; ++nt) { colS[nt] = 0.f; colQ[nt] = 0.f; }
#pragma unroll
  for (int mt = 0; mt < 2; ++mt) {
#pragma unroll
    for (int r = 0; r < 4; ++r) {
      const int m = bm + wave * 32 + mt * 16 + aq * 4 + r;   // C/D: row=quad*4+reg
      const int sid = srcids[m];
      const float* g = pre_src + (size_t)sid * 128;
      float* hp = hpath + (size_t)m * 128;
#pragma unroll
      for (int nt = 0; nt < 8; ++nt) {
        const int col = nt * 16 + am;                        // C/D: col=lane&15
        float v = acc[mt][nt][r] + g[col];
        hp[col] = v;
        colS[nt] += v;
        colQ[nt] += v * v;
      }
    }
  }
  // reduce cols across lane-quads (lanes l, l+16, l+32, l+48 share col = l&15)
#pragma unroll
  for (int nt = 0; nt < 8; ++nt) {
    colS[nt] += __shfl_xor(colS[nt], 16);
    colS[nt] += __shfl_xor(colS[nt], 32);
    colQ[nt] += __shfl_xor(colQ[nt], 16);
    colQ[nt] += __shfl_xor(colQ[nt], 32);
  }
  if (lane < 16) {
#pragma unroll
    for (int nt = 0; nt < 8; ++nt) {
      redS[wave][nt * 16 + lane] = colS[nt];
      redQ[wave][nt * 16 + lane] = colQ[nt];
    }
  }
  __syncthreads();
  if (tid < 128) {
    float s = redS[0][tid] + redS[1][tid] + redS[2][tid] + redS[3][tid];
    atomicAdd(colsum + tid, s);
  } else {
    int cn = tid - 128;
    float s = redQ[0][cn] + redQ[1][cn] + redQ[2][cn] + redQ[3][cn];
    atomicAdd(colsumsq + cn, s);
  }
}

// ---------------------------------------------------------------- stat finalize
__global__ void k_finT(float* __restrict__ st) {
  int j = threadIdx.x;  // 384
  float mean = st[j] * (1.0f / NSRC);
  float var = st[384 + j] * (1.0f / NSRC) - mean * mean;
  st[768 + j] = mean;
  st[1152 + j] = rsqrtf(var + 1e-5f);
}

__global__ void k_finP(float* __restrict__ st, const float* __restrict__ g,
                       const float* __restrict__ b) {
  int j = threadIdx.x;  // 128
  float mean = st[j] * (1.0f / NEDGE);
  float var = st[128 + j] * (1.0f / NEDGE) - mean * mean;
  float rstd = rsqrtf(var + 1e-5f);
  float a = g[j] * rstd;
  st[256 + j] = a;
  st[384 + j] = b[j] - a * mean;
}

// ---------------------------------------------------------------- scoring
__global__ __launch_bounds__(256) void k_score(const float* __restrict__ hpath,
                                               const float* __restrict__ aP,
                                               const float* __restrict__ cP,
                                               const float* __restrict__ w,
                                               float* __restrict__ scores) {
  const int row = blockIdx.x * 16 + (threadIdx.x >> 4);
  const int cg = threadIdx.x & 15;
  const float* hp = hpath + (size_t)row * 128 + cg * 8;
  const float4 x0 = *(const float4*)hp;
  const float4 x1 = *(const float4*)(hp + 4);
  const float xs[8] = {x0.x, x0.y, x0.z, x0.w, x1.x, x1.y, x1.z, x1.w};
  float part = 0.f;
#pragma unroll
  for (int q = 0; q < 8; ++q) {
    int j = cg * 8 + q;
    part += fmaxf(fmaf(aP[j], xs[q], cP[j]), 0.f) * w[j];
  }
#pragma unroll
  for (int o = 8; o >= 1; o >>= 1) part += __shfl_xor(part, o, 16);
  if (cg == 0) scores[row] = part;
}

// ---------------------------------------------------------------- top-k
__global__ __launch_bounds__(256) void k_top1(const float* __restrict__ scores,
                                              KV* __restrict__ cand) {
  KV t[TOPN];
#pragma unroll
  for (int q = 0; q < TOPN; ++q) { t[q].v = -INFINITY; t[q].i = 2147483647; }
  for (int e = blockIdx.x * 256 + threadIdx.x; e < NEDGE; e += 256 * 256) {
    float v = scores[e];
    if (v > t[TOPN - 1].v) {
      t[TOPN - 1].v = v;
      t[TOPN - 1].i = e;
#pragma unroll
      for (int q = TOPN - 1; q > 0; --q) {
        if (t[q].v > t[q - 1].v) { KV tmp = t[q - 1]; t[q - 1] = t[q]; t[q] = tmp; }
      }
    }
  }
  __shared__ KV sh[128][TOPN];
  int tid = threadIdx.x;
  for (int s = 128; s >= 1; s >>= 1) {
    if (tid >= s && tid < 2 * s) {
#pragma unroll
      for (int q = 0; q < TOPN; ++q) sh[tid - s][q] = t[q];
    }
    __syncthreads();
    if (tid < s) kv_merge(t, sh[tid]);
    __syncthreads();
  }
  if (tid == 0) {
#pragma unroll
    for (int q = 0; q < TOPN; ++q) cand[blockIdx.x * TOPN + q] = t[q];
  }
}

__global__ __launch_bounds__(256) void k_top2(const KV* __restrict__ cand,
                                              float* __restrict__ outTail) {
  int tid = threadIdx.x;
  KV t[TOPN];
#pragma unroll
  for (int q = 0; q < TOPN; ++q) t[q] = cand[tid * TOPN + q];
  __shared__ KV sh[128][TOPN];
  for (int s = 128; s >= 1; s >>= 1) {
    if (tid >= s && tid < 2 * s) {
#pragma unroll
      for (int q = 0; q < TOPN; ++q) sh[tid - s][q] = t[q];
    }
    __syncthreads();
    if (tid < s) kv_merge(t, sh[tid]);
    __syncthreads();
  }
  if (tid == 0) {
#pragma unroll
    for (int q = 0; q < TOPN; ++q) {
      outTail[q] = t[q].v;
      outTail[TOPN + q] = (float)t[q].i;
    }
  }
}

// ---------------------------------------------------------------- launch
extern "C" void kernel_launch(void* const* d_in, const int* in_sizes, int n_in,
                              void* d_out, int out_size, void* d_ws, size_t ws_size,
                              hipStream_t stream) {
  const float* paths_srcs = (const float*)d_in[0];
  const float* path_feats = (const float*)d_in[1];
  const int* src_ids = (const int*)d_in[2];
  const float* cew = (const float*)d_in[3];
  const float* ceb = (const float*)d_in[4];
  const float* cw1 = (const float*)d_in[5];
  const float* bng = (const float*)d_in[6];
  const float* bnbt = (const float*)d_in[7];
  const float* cw2 = (const float*)d_in[8];
  const float* l1w = (const float*)d_in[9];
  const float* l1b = (const float*)d_in[10];
  const float* l2w = (const float*)d_in[11];
  const float* l2b = (const float*)d_in[12];
  const float* psw = (const float*)d_in[13];
  const float* psb = (const float*)d_in[14];
  const float* ptw = (const float*)d_in[15];
  const float* ptb = (const float*)d_in[16];
  const float* pbg = (const float*)d_in[17];
  const float* pbb = (const float*)d_in[18];
  const float* scw = (const float*)d_in[19];
  float* out = (float*)d_out;
  float* ws = (float*)d_ws;

  // workspace layout (floats)
  float* w1cat = ws;                        // 49152
  float* wew1cat = w1cat + 49152;           // 90624
  float* bprime = wew1cat + 90624;          // 512
  float* m1 = bprime + 512;                 // 49152
  float* statsT = m1 + 49152;               // 1536: sum|sumsq|mean|rstd
  float* statsP = statsT + 1536;            // 512:  sum|sumsq|a|c
  float* agg = statsP + 512;                // 2360000
  float* T = agg + 2360000;                 // 3840000
  float* H1 = T + 3840000;                  // 1280000
  float* pre_src = H1 + 1280000;            // 1280000
  float* scores = pre_src + 1280000;        // 320000
  KV* cand = (KV*)(scores + 320000);        // 1536 KV = 3072 floats
  float* hpath = scores + 320000 + 3072;    // 40960000
  unsigned short* Bh = (unsigned short*)(hpath + 40960000);  // 32768 ushorts
  unsigned short* Bl = Bh + 32768;                           // 32768 ushorts
  // CSR arrays overlap the hpath region (dead before hpath is written)
  int* counts = (int*)hpath;                // 10000
  int* offsets = counts + 10000;            // 10001
  int* cursor = offsets + 10001;            // 10000
  int* elist = cursor + 10000;              // 320000
  const size_t needed = (size_t)(49152 + 90624 + 512 + 49152 + 1536 + 512 + 2360000 +
                                 3840000 + 1280000 + 1280000 + 320000 + 3072 +
                                 40960000 + 16384 + 16384) * 4;
  if (ws_size < needed) {
    k_sentinel<<<1, 64, 0, stream>>>(out);
    return;
  }

  const float* np = nullptr;

  // weight prep
  k_prep_w1cat<<<192, 256, 0, stream>>>(cw1, w1cat);
  k_prep_wew1<<<708, 128, 0, stream>>>(cew, cw1, wew1cat);
  k_prep_bprime<<<3, 128, 0, stream>>>(ceb, cw1, bprime);
  k_prep_m1<<<384, 128, 0, stream>>>(cw2, l1w, m1);
  k_prep_bsplit<<<128, 256, 0, stream>>>(ptw, Bh, Bl);

  // zero stat accumulators + CSR counts
  k_zero<<<8, 256, 0, stream>>>(statsT, 2048);
  k_zero<<<(10000 + 255) / 256, 256, 0, stream>>>((float*)counts, 10000);

  // CSR build + gather-based segment sum
  k_hist<<<(NEDGE + 255) / 256, 256, 0, stream>>>(src_ids, counts);
  k_scan<<<1, 256, 0, stream>>>(counts, offsets, cursor);
  k_scatter<<<(NEDGE + 255) / 256, 256, 0, stream>>>(src_ids, cursor, elist);
  k_gather<<<NSRC, 256, 0, stream>>>(path_feats, offsets, elist, agg);

  // node pipeline (fp32)
  gemm_k<0, 0><<<dim3(79, 3), 256, 0, stream>>>(paths_srcs, w1cat, T, NSRC, 128, 384,
                                                np, np, np, np, np, np, np, nullptr, np,
                                                nullptr, nullptr);
  gemm_k<0, 1><<<dim3(79, 3), 256, 0, stream>>>(agg, wew1cat, T, NSRC, EDIM, 384,
                                                np, np, np, np, bprime, np, T, nullptr,
                                                np, statsT, statsT + 384);
  k_finT<<<1, 384, 0, stream>>>(statsT);
  gemm_k<1, 2><<<dim3(79, 1), 256, 0, stream>>>(T, m1, H1, NSRC, 384, 128,
                                                bng, bnbt, statsT + 768, statsT + 1152,
                                                l1b, np, np, nullptr, np, nullptr, nullptr);
  gemm_k<0, 3><<<dim3(79, 1), 256, 0, stream>>>(H1, l2w, out, NSRC, 128, 128,
                                                np, np, np, np, l2b, np, np, nullptr, np,
                                                nullptr, nullptr);
  gemm_k<0, 3><<<dim3(79, 1), 256, 0, stream>>>(out, psw, pre_src, NSRC, 128, 128,
                                                np, np, np, np, psb, ptb, np, nullptr, np,
                                                nullptr, nullptr);

  // big GEMM: split-bf16 MFMA, fused gather + column stats
  k_hgemm<<<2500, 256, 0, stream>>>(path_feats, Bh, Bl, src_ids, pre_src, hpath,
                                    statsP, statsP + 128);
  k_finP<<<1, 128, 0, stream>>>(statsP, pbg, pbb);

  // scores + top-6
  k_score<<<NEDGE / 16, 256, 0, stream>>>(hpath, statsP + 256, statsP + 384, scw, scores);
  k_top1<<<256, 256, 0, stream>>>(scores, cand);
  k_top2<<<1, 256, 0, stream>>>(cand, out + (size_t)NSRC * 128);
}

// Round 4
// 990.097 us; speedup vs baseline: 1.9531x; 1.0832x over previous
//
#include <hip/hip_runtime.h>
#include <math.h>

#define NSRC 10000
#define NEDGE 320000
#define EDIM 236
#define TOPN 6

typedef __attribute__((ext_vector_type(8))) short short8;
typedef __attribute__((ext_vector_type(4))) float floatx4;

// ---------------------------------------------------------------- bf16 split
__device__ __forceinline__ unsigned short bf16_rne(float x) {
  union { float f; unsigned int u; } c; c.f = x;
  unsigned int r = (c.u + 0x7FFFu + ((c.u >> 16) & 1u)) >> 16;
  return (unsigned short)r;
}
__device__ __forceinline__ float bf16_to_f(unsigned short h) {
  union { unsigned int u; float f; } c; c.u = ((unsigned int)h) << 16;
  return c.f;
}
__device__ __forceinline__ void split_f32(float x, unsigned short& h, unsigned short& l) {
  h = bf16_rne(x);
  l = bf16_rne(x - bf16_to_f(h));
}

// ---------------------------------------------------------------- top-k utils
struct KV { float v; int i; };

__device__ __forceinline__ bool kv_better(const KV a, const KV b) {
  return (a.v > b.v) || (a.v == b.v && a.i < b.i);
}

__device__ __forceinline__ void kv_merge(KV d[TOPN], const KV o[TOPN]) {
  KV r[TOPN];
  int ia = 0, ib = 0;
#pragma unroll
  for (int q = 0; q < TOPN; ++q) {
    bool takeA;
    if (ia >= TOPN) takeA = false;
    else if (ib >= TOPN) takeA = true;
    else takeA = kv_better(d[ia], o[ib]);
    r[q] = takeA ? d[ia] : o[ib];
    if (takeA) ia++; else ib++;
  }
#pragma unroll
  for (int q = 0; q < TOPN; ++q) d[q] = r[q];
}

__global__ void k_sentinel(float* __restrict__ out) {
  if (threadIdx.x == 0) out[0] = 1.0e9f;
}

// ---------------------------------------------------------------- mega prep
// role-dispatched: all weight prep + accumulator zeroing in ONE launch.
// blocks: [0,708) wew1 | [708,1092) m1 | [1092,1284) w1cat | [1284,1287) bprime
//         [1287,1415) bsplit | [1415,1543) bcat | [1543,1551) zero stats
//         [1551,1591) zero counts
__global__ __launch_bounds__(256)
void k_prep_all(const float* __restrict__ cew, const float* __restrict__ ceb,
                const float* __restrict__ cw1, const float* __restrict__ cw2,
                const float* __restrict__ l1w, const float* __restrict__ l2w,
                const float* __restrict__ psw, const float* __restrict__ l2b,
                const float* __restrict__ psb, const float* __restrict__ ptb,
                const float* __restrict__ ptw,
                float* __restrict__ w1cat, float* __restrict__ wew1cat,
                float* __restrict__ bprime, float* __restrict__ m1,
                unsigned short* __restrict__ Bh, unsigned short* __restrict__ Bl,
                float* __restrict__ bcat, float* __restrict__ biascat,
                float* __restrict__ statsT, int* __restrict__ counts) {
  const int b = blockIdx.x;
  const int tid = threadIdx.x;
  if (b < 708) {                      // wew1cat[k][i*128+j] = sum_m We_i[k][m]*W1_i[m][j]
    if (tid >= 128) return;
    int i = b / EDIM;
    int k = b - i * EDIM;
    const float* we = cew + ((size_t)i * EDIM + k) * 128;
    const float* w1 = cw1 + (size_t)i * 16384;
    float acc = 0.f;
    for (int m = 0; m < 128; ++m) acc = fmaf(we[m], w1[m * 128 + tid], acc);
    wew1cat[k * 384 + i * 128 + tid] = acc;
  } else if (b < 1092) {              // m1[(i*128+r)][j] = sum_c W2_i[r][c]*lin1_W[(i*128+c)][j]
    if (tid >= 128) return;
    int bb = b - 708;
    int i = bb >> 7;
    int r = bb & 127;
    const float* w2 = cw2 + (size_t)i * 16384 + r * 128;
    float acc = 0.f;
    for (int c = 0; c < 128; ++c) acc = fmaf(w2[c], l1w[((size_t)i * 128 + c) * 128 + tid], acc);
    m1[bb * 128 + tid] = acc;
  } else if (b < 1284) {              // w1cat transpose-copy
    int gid = (b - 1092) * 256 + tid;
    if (gid >= 3 * 128 * 128) return;
    int i = gid >> 14;
    int m = (gid >> 7) & 127;
    int j = gid & 127;
    w1cat[m * 384 + i * 128 + j] = cw1[gid];
  } else if (b < 1287) {              // bprime[i*128+j] = sum_m be_i[m]*W1_i[m][j]
    if (tid >= 128) return;
    int i = b - 1284;
    const float* be = ceb + i * 128;
    const float* w1 = cw1 + (size_t)i * 16384;
    float acc = 0.f;
    for (int m = 0; m < 128; ++m) acc = fmaf(be[m], w1[m * 128 + tid], acc);
    bprime[i * 128 + tid] = acc;
  } else if (b < 1415) {              // B split: ptw [236][128] -> Bh/Bl [128][256]
    int n = b - 1287;
    float v = (tid < EDIM) ? ptw[(size_t)tid * 128 + n] : 0.f;
    unsigned short h, l;
    split_f32(v, h, l);
    Bh[n * 256 + tid] = h;
    Bl[n * 256 + tid] = l;
  } else if (b < 1543) {              // bcat [128][256] = [l2w | l2w@psw]; biascat
    if (tid >= 128) return;
    int k = b - 1415;
    bcat[k * 256 + tid] = l2w[k * 128 + tid];
    float acc = 0.f;
    for (int c = 0; c < 128; ++c) acc = fmaf(l2w[k * 128 + c], psw[c * 128 + tid], acc);
    bcat[k * 256 + 128 + tid] = acc;
    if (k == 0) {
      biascat[tid] = l2b[tid];
      float bb = 0.f;
      for (int c = 0; c < 128; ++c) bb = fmaf(l2b[c], psw[c * 128 + tid], bb);
      biascat[128 + tid] = bb + psb[tid] + ptb[tid];
    }
  } else if (b < 1551) {              // zero statsT(1536)+statsP(512)
    int i = (b - 1543) * 256 + tid;
    if (i < 2048) statsT[i] = 0.f;
  } else {                            // zero counts(10000)
    int i = (b - 1551) * 256 + tid;
    if (i < NSRC) counts[i] = 0;
  }
}

// ---------------------------------------------------------------- CSR build
__global__ __launch_bounds__(256) void k_hist(const int* __restrict__ src,
                                              int* __restrict__ counts) {
  int e = blockIdx.x * 256 + threadIdx.x;
  if (e < NEDGE) atomicAdd(&counts[src[e]], 1);
}

__global__ __launch_bounds__(256) void k_scan(const int* __restrict__ counts,
                                              int* __restrict__ offsets,
                                              int* __restrict__ cursor) {
  __shared__ int part[256];
  const int t = threadIdx.x;
  const int base = t * 40;
  int s = 0;
  for (int k = 0; k < 40; ++k) {
    int i = base + k;
    if (i < NSRC) s += counts[i];
  }
  part[t] = s;
  __syncthreads();
  for (int off = 1; off < 256; off <<= 1) {
    int v = (t >= off) ? part[t - off] : 0;
    __syncthreads();
    part[t] += v;
    __syncthreads();
  }
  int run = (t == 0) ? 0 : part[t - 1];
  for (int k = 0; k < 40; ++k) {
    int i = base + k;
    if (i < NSRC) {
      offsets[i] = run;
      cursor[i] = run;
      run += counts[i];
    }
  }
  if (t == 255) offsets[NSRC] = run;
}

__global__ __launch_bounds__(256) void k_scatter(const int* __restrict__ src,
                                                 int* __restrict__ cursor,
                                                 int* __restrict__ elist) {
  int e = blockIdx.x * 256 + threadIdx.x;
  if (e < NEDGE) {
    int p = atomicAdd(&cursor[src[e]], 1);
    elist[p] = e;
  }
}

// agg[row][t] = sum over row's edges of relu(pf[e][t]); LDS id prefetch + 4-deep unroll
__global__ __launch_bounds__(256) void k_gather(const float* __restrict__ pf,
                                                const int* __restrict__ offsets,
                                                const int* __restrict__ elist,
                                                float* __restrict__ agg) {
  const int row = blockIdx.x;
  const int t = threadIdx.x;
  __shared__ int sid[64];
  const int beg = offsets[row];
  const int end = offsets[row + 1];
  float a0 = 0.f, a1 = 0.f, a2 = 0.f, a3 = 0.f;
  for (int b = beg; b < end; b += 64) {
    const int cnt = min(64, end - b);
    __syncthreads();
    if (t < cnt) sid[t] = elist[b + t];
    __syncthreads();
    if (t < EDIM) {
      int e = 0;
      for (; e + 4 <= cnt; e += 4) {
        int i0 = sid[e], i1 = sid[e + 1], i2 = sid[e + 2], i3 = sid[e + 3];
        a0 += fmaxf(pf[(size_t)i0 * EDIM + t], 0.f);
        a1 += fmaxf(pf[(size_t)i1 * EDIM + t], 0.f);
        a2 += fmaxf(pf[(size_t)i2 * EDIM + t], 0.f);
        a3 += fmaxf(pf[(size_t)i3 * EDIM + t], 0.f);
      }
      for (; e < cnt; ++e) a0 += fmaxf(pf[(size_t)sid[e] * EDIM + t], 0.f);
    }
  }
  if (t < EDIM) agg[(size_t)row * EDIM + t] = (a0 + a1) + (a2 + a3);
}

// ---------------------------------------------------------------- merged T GEMM
// T[10000,384] = paths_srcs[10000,128]@w1cat[128,384] + agg[10000,236]@wew1cat[236,384]
//              + bprime; column sum/sumsq -> statsT raw sums
__global__ __launch_bounds__(256)
void k_gemmT(const float* __restrict__ A1, const float* __restrict__ B1,
             const float* __restrict__ A2, const float* __restrict__ B2,
             const float* __restrict__ bias, float* __restrict__ C,
             float* __restrict__ colsum, float* __restrict__ colsumsq) {
  __shared__ float As[8][128];
  __shared__ float Bs[8][128];
  __shared__ float red[16][128];
  const int tid = threadIdx.x;
  const int tx = tid & 15;
  const int ty = tid >> 4;
  const int bm = blockIdx.x * 128;
  const int bn = blockIdx.y * 128;
  const int N = 384;

  float acc[8][8];
#pragma unroll
  for (int i = 0; i < 8; ++i)
#pragma unroll
    for (int j = 0; j < 8; ++j) acc[i][j] = 0.f;

#pragma unroll 1
  for (int seg = 0; seg < 2; ++seg) {
    const float* A = seg ? A2 : A1;
    const float* B = seg ? B2 : B1;
    const int K = seg ? EDIM : 128;
    for (int k0 = 0; k0 < K; k0 += 8) {
      {
        int r = tid >> 1;
        int cq = (tid & 1) << 2;
        float4 v = make_float4(0.f, 0.f, 0.f, 0.f);
        int row = bm + r;
        if (row < NSRC) {
          const float* ap = A + (size_t)row * K + k0 + cq;
          if (k0 + cq + 4 <= K) {
            v = *(const float4*)ap;
          } else {
            float tmp[4] = {0.f, 0.f, 0.f, 0.f};
            for (int q = 0; q < 4; ++q)
              if (k0 + cq + q < K) tmp[q] = ap[q];
            v = make_float4(tmp[0], tmp[1], tmp[2], tmp[3]);
          }
        }
        As[cq + 0][r] = v.x;
        As[cq + 1][r] = v.y;
        As[cq + 2][r] = v.z;
        As[cq + 3][r] = v.w;
      }
      {
        int r = tid >> 5;
        int c = (tid & 31) << 2;
        float4 v = make_float4(0.f, 0.f, 0.f, 0.f);
        int kk = k0 + r;
        if (kk < K) v = *(const float4*)(B + (size_t)kk * N + bn + c);
        *(float4*)&Bs[r][c] = v;
      }
      __syncthreads();
#pragma unroll
      for (int kk = 0; kk < 8; ++kk) {
        const float4 a0 = *(const float4*)&As[kk][ty * 8];
        const float4 a1 = *(const float4*)&As[kk][ty * 8 + 4];
        const float4 b0 = *(const float4*)&Bs[kk][tx * 8];
        const float4 b1 = *(const float4*)&Bs[kk][tx * 8 + 4];
        const float av[8] = {a0.x, a0.y, a0.z, a0.w, a1.x, a1.y, a1.z, a1.w};
        const float bv[8] = {b0.x, b0.y, b0.z, b0.w, b1.x, b1.y, b1.z, b1.w};
#pragma unroll
        for (int i = 0; i < 8; ++i)
#pragma unroll
          for (int j = 0; j < 8; ++j) acc[i][j] = fmaf(av[i], bv[j], acc[i][j]);
      }
      __syncthreads();
    }
  }

  const int nb = bn + tx * 8;
  float colS[8], colQ[8];
#pragma unroll
  for (int j = 0; j < 8; ++j) { colS[j] = 0.f; colQ[j] = 0.f; }
#pragma unroll
  for (int i = 0; i < 8; ++i) {
    int m = bm + ty * 8 + i;
    if (m < NSRC) {
      float outv[8];
#pragma unroll
      for (int j = 0; j < 8; ++j) outv[j] = acc[i][j] + bias[nb + j];
      float* crow = C + (size_t)m * N + nb;
      *(float4*)crow = make_float4(outv[0], outv[1], outv[2], outv[3]);
      *(float4*)(crow + 4) = make_float4(outv[4], outv[5], outv[6], outv[7]);
#pragma unroll
      for (int j = 0; j < 8; ++j) { colS[j] += outv[j]; colQ[j] += outv[j] * outv[j]; }
    }
  }
  *(float4*)&red[ty][tx * 8] = make_float4(colS[0], colS[1], colS[2], colS[3]);
  *(float4*)&red[ty][tx * 8 + 4] = make_float4(colS[4], colS[5], colS[6], colS[7]);
  __syncthreads();
  if (tid < 128) {
    float s = 0.f;
#pragma unroll
    for (int t = 0; t < 16; ++t) s += red[t][tid];
    atomicAdd(colsum + bn + tid, s);
  }
  __syncthreads();
  *(float4*)&red[ty][tx * 8] = make_float4(colQ[0], colQ[1], colQ[2], colQ[3]);
  *(float4*)&red[ty][tx * 8 + 4] = make_float4(colQ[4], colQ[5], colQ[6], colQ[7]);
  __syncthreads();
  if (tid < 128) {
    float s = 0.f;
#pragma unroll
    for (int t = 0; t < 16; ++t) s += red[t][tid];
    atomicAdd(colsumsq + bn + tid, s);
  }
}

// ---------------------------------------------------------------- fp32 GEMM (node)
// ATR: 0=none, 2=BN from raw sums + relu on A-load
// EPI: 2=relu(acc+bias); 5=dual-out: col<128 -> C, col>=128 -> colsum(as C2), both stride 128
template <int ATR, int EPI>
__global__ __launch_bounds__(256)
void gemm_k(const float* __restrict__ A, const float* __restrict__ B,
            float* __restrict__ C, int M, int K, int N,
            const float* __restrict__ bn_g, const float* __restrict__ bn_b,
            const float* __restrict__ rawS, const float* __restrict__ rawQ,
            const float* __restrict__ bias, float* __restrict__ C2) {
  __shared__ float As[8][128];
  __shared__ float Bs[8][128];
  const int tid = threadIdx.x;
  const int tx = tid & 15;
  const int ty = tid >> 4;
  const int bm = blockIdx.x * 128;
  const int bn = blockIdx.y * 128;

  float acc[8][8];
#pragma unroll
  for (int i = 0; i < 8; ++i)
#pragma unroll
    for (int j = 0; j < 8; ++j) acc[i][j] = 0.f;

  for (int k0 = 0; k0 < K; k0 += 8) {
    {
      int r = tid >> 1;
      int cq = (tid & 1) << 2;
      float4 v = make_float4(0.f, 0.f, 0.f, 0.f);
      int row = bm + r;
      if (row < M) {
        const float* ap = A + (size_t)row * K + k0 + cq;
        if (k0 + cq + 4 <= K) {
          v = *(const float4*)ap;
        } else {
          float tmp[4] = {0.f, 0.f, 0.f, 0.f};
          for (int q = 0; q < 4; ++q)
            if (k0 + cq + q < K) tmp[q] = ap[q];
          v = make_float4(tmp[0], tmp[1], tmp[2], tmp[3]);
        }
      }
      if constexpr (ATR == 2) {
        float vv[4] = {v.x, v.y, v.z, v.w};
#pragma unroll
        for (int q = 0; q < 4; ++q) {
          int k = k0 + cq + q;
          if (k < K) {
            float mean = rawS[k] * (1.0f / NSRC);
            float var = rawQ[k] * (1.0f / NSRC) - mean * mean;
            float rstd = rsqrtf(var + 1e-5f);
            vv[q] = fmaxf(fmaf(bn_g[k] * rstd, vv[q] - mean, bn_b[k]), 0.f);
          } else {
            vv[q] = 0.f;
          }
        }
        v = make_float4(vv[0], vv[1], vv[2], vv[3]);
      }
      As[cq + 0][r] = v.x;
      As[cq + 1][r] = v.y;
      As[cq + 2][r] = v.z;
      As[cq + 3][r] = v.w;
    }
    {
      int r = tid >> 5;
      int c = (tid & 31) << 2;
      float4 v = make_float4(0.f, 0.f, 0.f, 0.f);
      int kk = k0 + r;
      if (kk < K) v = *(const float4*)(B + (size_t)kk * N + bn + c);
      *(float4*)&Bs[r][c] = v;
    }
    __syncthreads();
#pragma unroll
    for (int kk = 0; kk < 8; ++kk) {
      const float4 a0 = *(const float4*)&As[kk][ty * 8];
      const float4 a1 = *(const float4*)&As[kk][ty * 8 + 4];
      const float4 b0 = *(const float4*)&Bs[kk][tx * 8];
      const float4 b1 = *(const float4*)&Bs[kk][tx * 8 + 4];
      const float av[8] = {a0.x, a0.y, a0.z, a0.w, a1.x, a1.y, a1.z, a1.w};
      const float bv[8] = {b0.x, b0.y, b0.z, b0.w, b1.x, b1.y, b1.z, b1.w};
#pragma unroll
      for (int i = 0; i < 8; ++i)
#pragma unroll
        for (int j = 0; j < 8; ++j) acc[i][j] = fmaf(av[i], bv[j], acc[i][j]);
    }
    __syncthreads();
  }

  const int nb = bn + tx * 8;
#pragma unroll
  for (int i = 0; i < 8; ++i) {
    int m = bm + ty * 8 + i;
    if (m < M) {
      float outv[8];
#pragma unroll
      for (int j = 0; j < 8; ++j) {
        outv[j] = acc[i][j] + bias[nb + j];
        if constexpr (EPI == 2) outv[j] = fmaxf(outv[j], 0.f);
      }
      float* crow;
      if constexpr (EPI == 5) {
        crow = (nb < 128) ? (C + (size_t)m * 128 + nb) : (C2 + (size_t)m * 128 + (nb - 128));
      } else {
        crow = C + (size_t)m * N + nb;
      }
      *(float4*)crow = make_float4(outv[0], outv[1], outv[2], outv[3]);
      *(float4*)(crow + 4) = make_float4(outv[4], outv[5], outv[6], outv[7]);
    }
  }
}

// ---------------------------------------------------------------- big GEMM: split-bf16 MFMA
// hpath[320000,128] = path_feats @ pe_tgt_W + pre_src[srcids[m]]; col sum/sumsq.
// A fragments load global->register (no LDS); B staged in LDS per 32-k chunk.
__global__ __launch_bounds__(256)
void k_hgemm(const float* __restrict__ A, const unsigned short* __restrict__ Bh,
             const unsigned short* __restrict__ Bl, const int* __restrict__ srcids,
             const float* __restrict__ pre_src, float* __restrict__ hpath,
             float* __restrict__ colsum, float* __restrict__ colsumsq) {
  // pitch 40 bf16 = 80 B: fragment b128 reads are <=2-way bank aliased (free)
  __shared__ __align__(16) unsigned short Bhs[128][40];
  __shared__ __align__(16) unsigned short Bls[128][40];
  __shared__ float redS[4][128];
  __shared__ float redQ[4][128];

  const int tid = threadIdx.x;
  const int wave = tid >> 6;
  const int lane = tid & 63;
  const int am = lane & 15;
  const int aq = lane >> 4;
  const int bm = blockIdx.x * 128;

  floatx4 acc[2][8];
#pragma unroll
  for (int mt = 0; mt < 2; ++mt)
#pragma unroll
    for (int nt = 0; nt < 8; ++nt) acc[mt][nt] = (floatx4){0.f, 0.f, 0.f, 0.f};

  const int rowS = tid >> 1;          // B staging row
  const int kq = (tid & 1) * 16;      // B staging k offset
  const float* a0p = A + (size_t)(bm + wave * 32 + am) * EDIM;   // 16B-aligned (944=59*16)
  const float* a1p = a0p + 16 * EDIM;

  for (int c = 0; c < 8; ++c) {
    const int k0 = c * 32;
    // ---- stage B chunk into LDS ----
    {
      const unsigned short* bhp = Bh + (size_t)rowS * 256 + k0 + kq;
      const unsigned short* blp = Bl + (size_t)rowS * 256 + k0 + kq;
      *(short8*)&Bhs[rowS][kq] = *(const short8*)bhp;
      *(short8*)&Bhs[rowS][kq + 8] = *(const short8*)(bhp + 8);
      *(short8*)&Bls[rowS][kq] = *(const short8*)blp;
      *(short8*)&Bls[rowS][kq + 8] = *(const short8*)(blp + 8);
    }
    // ---- A fragments: global -> registers, split in-register ----
    const int kA = k0 + aq * 8;
    float av0[8], av1[8];
    if (kA + 8 <= EDIM) {
      float4 x = *(const float4*)(a0p + kA);
      float4 y = *(const float4*)(a0p + kA + 4);
      av0[0] = x.x; av0[1] = x.y; av0[2] = x.z; av0[3] = x.w;
      av0[4] = y.x; av0[5] = y.y; av0[6] = y.z; av0[7] = y.w;
      x = *(const float4*)(a1p + kA);
      y = *(const float4*)(a1p + kA + 4);
      av1[0] = x.x; av1[1] = x.y; av1[2] = x.z; av1[3] = x.w;
      av1[4] = y.x; av1[5] = y.y; av1[6] = y.z; av1[7] = y.w;
    } else {
#pragma unroll
      for (int q = 0; q < 8; ++q) {
        int k = kA + q;
        av0[q] = (k < EDIM) ? a0p[k] : 0.f;
        av1[q] = (k < EDIM) ? a1p[k] : 0.f;
      }
    }
    short8 ah0, al0, ah1, al1;
#pragma unroll
    for (int q = 0; q < 8; ++q) {
      unsigned short h, l;
      split_f32(av0[q], h, l);
      ah0[q] = (short)h; al0[q] = (short)l;
      split_f32(av1[q], h, l);
      ah1[q] = (short)h; al1[q] = (short)l;
    }
    __syncthreads();
    // ---- MFMA ----
#pragma unroll
    for (int nt = 0; nt < 8; ++nt) {
      const short8 bh = *(const short8*)&Bhs[nt * 16 + am][aq * 8];
      const short8 bl = *(const short8*)&Bls[nt * 16 + am][aq * 8];
      acc[0][nt] = __builtin_amdgcn_mfma_f32_16x16x32_bf16(ah0, bl, acc[0][nt], 0, 0, 0);
      acc[1][nt] = __builtin_amdgcn_mfma_f32_16x16x32_bf16(ah1, bl, acc[1][nt], 0, 0, 0);
      acc[0][nt] = __builtin_amdgcn_mfma_f32_16x16x32_bf16(al0, bh, acc[0][nt], 0, 0, 0);
      acc[1][nt] = __builtin_amdgcn_mfma_f32_16x16x32_bf16(al1, bh, acc[1][nt], 0, 0, 0);
      acc[0][nt] = __builtin_amdgcn_mfma_f32_16x16x32_bf16(ah0, bh, acc[0][nt], 0, 0, 0);
      acc[1][nt] = __builtin_amdgcn_mfma_f32_16x16x32_bf16(ah1, bh, acc[1][nt], 0, 0, 0);
    }
    __syncthreads();
  }

  // ---- epilogue: + pre_src[srcids[m]], store, column stats ----
  float colS[8], colQ[8];
#pragma unroll
  for (int nt = 0; nt < 8; ++nt) { colS[nt] = 0.f; colQ[nt] = 0.f; }
#pragma unroll
  for (int mt = 0; mt < 2; ++mt) {
#pragma unroll
    for (int r = 0; r < 4; ++r) {
      const int m = bm + wave * 32 + mt * 16 + aq * 4 + r;   // C/D: row=quad*4+reg
      const int sid = srcids[m];
      const float* g = pre_src + (size_t)sid * 128;
      float* hp = hpath + (size_t)m * 128;
#pragma unroll
      for (int nt = 0; nt < 8; ++nt) {
        const int col = nt * 16 + am;                        // C/D: col=lane&15
        float v = acc[mt][nt][r] + g[col];
        hp[col] = v;
        colS[nt] += v;
        colQ[nt] += v * v;
      }
    }
  }
#pragma unroll
  for (int nt = 0; nt < 8; ++nt) {
    colS[nt] += __shfl_xor(colS[nt], 16);
    colS[nt] += __shfl_xor(colS[nt], 32);
    colQ[nt] += __shfl_xor(colQ[nt], 16);
    colQ[nt] += __shfl_xor(colQ[nt], 32);
  }
  if (lane < 16) {
#pragma unroll
    for (int nt = 0; nt < 8; ++nt) {
      redS[wave][nt * 16 + lane] = colS[nt];
      redQ[wave][nt * 16 + lane] = colQ[nt];
    }
  }
  __syncthreads();
  if (tid < 128) {
    float s = redS[0][tid] + redS[1][tid] + redS[2][tid] + redS[3][tid];
    atomicAdd(colsum + tid, s);
  } else {
    int cn = tid - 128;
    float s = redQ[0][cn] + redQ[1][cn] + redQ[2][cn] + redQ[3][cn];
    atomicAdd(colsumsq + cn, s);
  }
}

// ---------------------------------------------------------------- fused BN+score+top1
// per 16-lane group: BN coeffs from raw sums (registers), grid-stride rows,
// per-thread top-6, block merge -> cand
__global__ __launch_bounds__(256)
void k_scoretop(const float* __restrict__ hpath, const float* __restrict__ stP,
                const float* __restrict__ g, const float* __restrict__ b,
                const float* __restrict__ w, KV* __restrict__ cand) {
  const int tid = threadIdx.x;
  const int cg = tid & 15;
  const int grp = (blockIdx.x * 256 + tid) >> 4;   // 0..4095
  float a8[8], c8[8], w8[8];
#pragma unroll
  for (int q = 0; q < 8; ++q) {
    int j = cg * 8 + q;
    float mean = stP[j] * (1.0f / NEDGE);
    float var = stP[128 + j] * (1.0f / NEDGE) - mean * mean;
    float rstd = rsqrtf(var + 1e-5f);
    float aj = g[j] * rstd;
    a8[q] = aj;
    c8[q] = b[j] - aj * mean;
    w8[q] = w[j];
  }
  KV t[TOPN];
#pragma unroll
  for (int q = 0; q < TOPN; ++q) { t[q].v = -INFINITY; t[q].i = 2147483647; }
  for (int row = grp; row < NEDGE; row += 4096) {
    const float* hp = hpath + (size_t)row * 128 + cg * 8;
    const float4 x0 = *(const float4*)hp;
    const float4 x1 = *(const float4*)(hp + 4);
    const float xs[8] = {x0.x, x0.y, x0.z, x0.w, x1.x, x1.y, x1.z, x1.w};
    float part = 0.f;
#pragma unroll
    for (int q = 0; q < 8; ++q)
      part += fmaxf(fmaf(a8[q], xs[q], c8[q]), 0.f) * w8[q];
#pragma unroll
    for (int o = 8; o >= 1; o >>= 1) part += __shfl_xor(part, o, 16);
    if (cg == 0 && part > t[TOPN - 1].v) {
      t[TOPN - 1].v = part;
      t[TOPN - 1].i = row;
#pragma unroll
      for (int q = TOPN - 1; q > 0; --q) {
        if (t[q].v > t[q - 1].v) { KV tmp = t[q - 1]; t[q - 1] = t[q]; t[q] = tmp; }
      }
    }
  }
  __shared__ KV sh[128][TOPN];
  for (int s = 128; s >= 1; s >>= 1) {
    if (tid >= s && tid < 2 * s) {
#pragma unroll
      for (int q = 0; q < TOPN; ++q) sh[tid - s][q] = t[q];
    }
    __syncthreads();
    if (tid < s) kv_merge(t, sh[tid]);
    __syncthreads();
  }
  if (tid == 0) {
#pragma unroll
    for (int q = 0; q < TOPN; ++q) cand[blockIdx.x * TOPN + q] = t[q];
  }
}

__global__ __launch_bounds__(256) void k_top2(const KV* __restrict__ cand,
                                              float* __restrict__ outTail) {
  int tid = threadIdx.x;
  KV t[TOPN];
#pragma unroll
  for (int q = 0; q < TOPN; ++q) t[q] = cand[tid * TOPN + q];
  __shared__ KV sh[128][TOPN];
  for (int s = 128; s >= 1; s >>= 1) {
    if (tid >= s && tid < 2 * s) {
#pragma unroll
      for (int q = 0; q < TOPN; ++q) sh[tid - s][q] = t[q];
    }
    __syncthreads();
    if (tid < s) kv_merge(t, sh[tid]);
    __syncthreads();
  }
  if (tid == 0) {
#pragma unroll
    for (int q = 0; q < TOPN; ++q) {
      outTail[q] = t[q].v;
      outTail[TOPN + q] = (float)t[q].i;
    }
  }
}

// ---------------------------------------------------------------- launch
extern "C" void kernel_launch(void* const* d_in, const int* in_sizes, int n_in,
                              void* d_out, int out_size, void* d_ws, size_t ws_size,
                              hipStream_t stream) {
  const float* paths_srcs = (const float*)d_in[0];
  const float* path_feats = (const float*)d_in[1];
  const int* src_ids = (const int*)d_in[2];
  const float* cew = (const float*)d_in[3];
  const float* ceb = (const float*)d_in[4];
  const float* cw1 = (const float*)d_in[5];
  const float* bng = (const float*)d_in[6];
  const float* bnbt = (const float*)d_in[7];
  const float* cw2 = (const float*)d_in[8];
  const float* l1w = (const float*)d_in[9];
  const float* l1b = (const float*)d_in[10];
  const float* l2w = (const float*)d_in[11];
  const float* l2b = (const float*)d_in[12];
  const float* psw = (const float*)d_in[13];
  const float* psb = (const float*)d_in[14];
  const float* ptw = (const float*)d_in[15];
  const float* ptb = (const float*)d_in[16];
  const float* pbg = (const float*)d_in[17];
  const float* pbb = (const float*)d_in[18];
  const float* scw = (const float*)d_in[19];
  float* out = (float*)d_out;
  float* ws = (float*)d_ws;

  // workspace layout (floats)
  float* w1cat = ws;                        // 49152
  float* wew1cat = w1cat + 49152;           // 90624
  float* bprime = wew1cat + 90624;          // 512
  float* m1 = bprime + 512;                 // 49152
  float* statsT = m1 + 49152;               // 1536 (raw S[384] | raw Q[384] | spare)
  float* statsP = statsT + 1536;            // 512 (raw S[128] | raw Q[128] | spare)
  float* agg = statsP + 512;                // 2360000
  float* T = agg + 2360000;                 // 3840000
  float* H1 = T + 3840000;                  // 1280000
  float* pre_src = H1 + 1280000;            // 1280000
  float* scores_dead = pre_src + 1280000;   // 320000 (unused, kept for layout stability)
  KV* cand = (KV*)(scores_dead + 320000);   // 1536 KV = 3072 floats
  float* hpath = scores_dead + 320000 + 3072; // 40960000
  unsigned short* Bh = (unsigned short*)(hpath + 40960000);  // 32768 ushorts
  unsigned short* Bl = Bh + 32768;                           // 32768 ushorts
  float* bcat = (float*)(Bl + 32768);       // 32768
  float* biascat = bcat + 32768;            // 256
  // CSR arrays overlap the hpath region (dead before hpath is written)
  int* counts = (int*)hpath;                // 10000
  int* offsets = counts + 10000;            // 10001
  int* cursor = offsets + 10001;            // 10000
  int* elist = cursor + 10000;              // 320000
  const size_t needed = (size_t)(49152 + 90624 + 512 + 49152 + 1536 + 512 + 2360000 +
                                 3840000 + 1280000 + 1280000 + 320000 + 3072 +
                                 40960000 + 16384 + 16384 + 32768 + 256) * 4;
  if (ws_size < needed) {
    k_sentinel<<<1, 64, 0, stream>>>(out);
    return;
  }

  // 1. all weight prep + zeroing
  k_prep_all<<<1591, 256, 0, stream>>>(cew, ceb, cw1, cw2, l1w, l2w, psw, l2b, psb, ptb,
                                       ptw, w1cat, wew1cat, bprime, m1, Bh, Bl,
                                       bcat, biascat, statsT, counts);
  // 2-5. CSR build + gather segment-sum
  k_hist<<<(NEDGE + 255) / 256, 256, 0, stream>>>(src_ids, counts);
  k_scan<<<1, 256, 0, stream>>>(counts, offsets, cursor);
  k_scatter<<<(NEDGE + 255) / 256, 256, 0, stream>>>(src_ids, cursor, elist);
  k_gather<<<NSRC, 256, 0, stream>>>(path_feats, offsets, elist, agg);
  // 6. T = ps@W1cat + agg@WeW1cat + bprime, raw stats
  k_gemmT<<<dim3(79, 3), 256, 0, stream>>>(paths_srcs, w1cat, agg, wew1cat, bprime, T,
                                           statsT, statsT + 384);
  // 7. H1 = relu(relu(BN(T))@M1 + l1b)  (BN from raw sums)
  gemm_k<2, 2><<<dim3(79, 1), 256, 0, stream>>>(T, m1, H1, NSRC, 384, 128,
                                                bng, bnbt, statsT, statsT + 384,
                                                l1b, nullptr);
  // 8. [node_emb | pre_src] = H1 @ [l2w | l2w@psw] + biascat
  gemm_k<0, 5><<<dim3(79, 2), 256, 0, stream>>>(H1, bcat, out, NSRC, 128, 256,
                                                nullptr, nullptr, nullptr, nullptr,
                                                biascat, pre_src);
  // 9. big GEMM (split-bf16 MFMA) + gather + stats
  k_hgemm<<<2500, 256, 0, stream>>>(path_feats, Bh, Bl, src_ids, pre_src, hpath,
                                    statsP, statsP + 128);
  // 10-11. fused BN+score+top1, then final merge
  k_scoretop<<<256, 256, 0, stream>>>(hpath, statsP, pbg, pbb, scw, cand);
  k_top2<<<1, 256, 0, stream>>>(cand, out + (size_t)NSRC * 128);
}